// Round 1
// baseline (2507.875 us; speedup 1.0000x reference)
//
#include <hip/hip_runtime.h>
#include <math.h>

#define NTH 256

// ============================= FPS =============================
// One block per batch. Exact numpy-order arithmetic ((dx*dx+dy*dy)+dz*dz, RN, no fma)
// and first-index tie-breaking on argmax so selected indices match the reference.
template<int N, int NPOINT>
__global__ __launch_bounds__(NTH) void fps_kernel(
    const float* __restrict__ xyz, float* __restrict__ out_xyz)
{
    constexpr int PT = N / NTH;
    __shared__ float pts[N * 3];
    __shared__ float rv[NTH / 64];
    __shared__ int   ri[NTH / 64];
    __shared__ int   rwin;
    const int tid = threadIdx.x;
    const int b = blockIdx.x;
    const float* src = xyz + (size_t)b * N * 3;
    for (int e = tid; e < N * 3; e += NTH) pts[e] = src[e];
    __syncthreads();

    float px[PT], py[PT], pz[PT], dist[PT];
#pragma unroll
    for (int j = 0; j < PT; ++j) {
        int i = j * NTH + tid;
        px[j] = pts[i * 3 + 0]; py[j] = pts[i * 3 + 1]; pz[j] = pts[i * 3 + 2];
        dist[j] = 1e10f;
    }
    if (tid == 0) {
        out_xyz[(size_t)(b * NPOINT) * 3 + 0] = pts[0];
        out_xyz[(size_t)(b * NPOINT) * 3 + 1] = pts[1];
        out_xyz[(size_t)(b * NPOINT) * 3 + 2] = pts[2];
    }
    int last = 0;
    for (int it = 1; it < NPOINT; ++it) {
        const float lx = pts[last * 3 + 0];
        const float ly = pts[last * 3 + 1];
        const float lz = pts[last * 3 + 2];
        float best = -1.f; int bi = 0;
#pragma unroll
        for (int j = 0; j < PT; ++j) {
            float dx = px[j] - lx, dy = py[j] - ly, dz = pz[j] - lz;
            float d = __fadd_rn(__fadd_rn(__fmul_rn(dx, dx), __fmul_rn(dy, dy)),
                                __fmul_rn(dz, dz));
            float nd = fminf(dist[j], d);
            dist[j] = nd;
            if (nd > best) { best = nd; bi = j * NTH + tid; }  // strict > keeps lowest idx
        }
#pragma unroll
        for (int off = 32; off > 0; off >>= 1) {
            float ov = __shfl_down(best, off);
            int   oi = __shfl_down(bi, off);
            if (ov > best || (ov == best && oi < bi)) { best = ov; bi = oi; }
        }
        if ((tid & 63) == 0) { rv[tid >> 6] = best; ri[tid >> 6] = bi; }
        __syncthreads();
        if (tid == 0) {
            float bv = rv[0]; int bx = ri[0];
#pragma unroll
            for (int wv = 1; wv < NTH / 64; ++wv)
                if (rv[wv] > bv || (rv[wv] == bv && ri[wv] < bx)) { bv = rv[wv]; bx = ri[wv]; }
            rwin = bx;
            out_xyz[((size_t)b * NPOINT + it) * 3 + 0] = pts[bx * 3 + 0];
            out_xyz[((size_t)b * NPOINT + it) * 3 + 1] = pts[bx * 3 + 1];
            out_xyz[((size_t)b * NPOINT + it) * 3 + 2] = pts[bx * 3 + 2];
        }
        __syncthreads();
        last = rwin;
    }
}

// ========================== Ball query ==========================
// One wave per center. Emits first 64 in-ball indices in ascending order,
// pads deficits with the first found index (N-1 if none, per clip()).
__global__ __launch_bounds__(NTH) void ball_query_kernel(
    const float* __restrict__ xyz, const float* __restrict__ centers,
    int* __restrict__ out, int BS, int N, int S, float r2)
{
    const int wid = blockIdx.x * (NTH / 64) + (threadIdx.x >> 6);
    if (wid >= BS) return;
    const int lane = threadIdx.x & 63;
    const int b = wid / S;
    const float cx = centers[(size_t)wid * 3 + 0];
    const float cy = centers[(size_t)wid * 3 + 1];
    const float cz = centers[(size_t)wid * 3 + 2];
    const float* px = xyz + (size_t)b * N * 3;
    int count = 0, first = -1;
    for (int base = 0; base < N && count < 64; base += 64) {
        int i = base + lane;
        float dx = px[i * 3 + 0] - cx, dy = px[i * 3 + 1] - cy, dz = px[i * 3 + 2] - cz;
        float d2 = __fadd_rn(__fadd_rn(__fmul_rn(dx, dx), __fmul_rn(dy, dy)),
                             __fmul_rn(dz, dz));
        bool inb = d2 < r2;
        unsigned long long m = __ballot(inb);
        if (first < 0 && m) first = base + (__ffsll(m) - 1);
        if (inb) {
            int pos = count + (int)__popcll(m & ((1ull << lane) - 1ull));
            if (pos < 64) out[(size_t)wid * 64 + pos] = i;
        }
        count += (int)__popcll(m);
    }
    int cnt = count > 64 ? 64 : count;
    if (first < 0) first = N - 1;
    if (lane >= cnt) out[(size_t)wid * 64 + lane] = first;
}

// ===================== Shared-MLP layer (LDS->LDS) =====================
// out[R][COUT] = relu(in[R][CINP] @ w * g + b). 256 threads; each thread owns
// column(s) o and RPT rows; weights cached in regs per K-chunk; LDS reads are
// wave-broadcast float4 (conflict-free).
template<int CIN, int CINP, int COUT, int R, int KC>
__device__ __forceinline__ void mlp_layer(
    const float* __restrict__ w, const float* __restrict__ gm, const float* __restrict__ bt,
    const float* __restrict__ in_lds, float* __restrict__ out_lds, int tid)
{
    constexpr int CPT    = (COUT > NTH) ? COUT / NTH : 1;
    constexpr int COLS   = (COUT > NTH) ? NTH : COUT;
    constexpr int GROUPS = NTH / COLS;
    constexpr int RPT    = R / GROUPS;
    constexpr int FULL   = CIN / KC;
    constexpr int TAIL   = CIN - FULL * KC;
    static_assert(R % GROUPS == 0, "rows not divisible");
    static_assert(CINP % KC == 0 && KC % 4 == 0, "chunking");

    const int o = tid % COLS;
    const int rbase = (tid / COLS) * RPT;
    const float* inp = in_lds + (size_t)rbase * CINP;

    float acc[RPT][CPT];
#pragma unroll
    for (int r = 0; r < RPT; ++r)
#pragma unroll
        for (int c = 0; c < CPT; ++c) acc[r][c] = 0.f;

    for (int kc = 0; kc < FULL; ++kc) {
        const int k0 = kc * KC;
        float wr[CPT][KC];
#pragma unroll
        for (int c = 0; c < CPT; ++c) {
            const float* wp = w + (size_t)k0 * COUT + o + c * NTH;
#pragma unroll
            for (int kk = 0; kk < KC; ++kk) wr[c][kk] = wp[(size_t)kk * COUT];
        }
#pragma unroll
        for (int r = 0; r < RPT; ++r) {
            const float4* ip = reinterpret_cast<const float4*>(inp + (size_t)r * CINP + k0);
#pragma unroll
            for (int q = 0; q < KC / 4; ++q) {
                float4 v = ip[q];
#pragma unroll
                for (int c = 0; c < CPT; ++c) {
                    acc[r][c] = fmaf(v.x, wr[c][4 * q + 0], acc[r][c]);
                    acc[r][c] = fmaf(v.y, wr[c][4 * q + 1], acc[r][c]);
                    acc[r][c] = fmaf(v.z, wr[c][4 * q + 2], acc[r][c]);
                    acc[r][c] = fmaf(v.w, wr[c][4 * q + 3], acc[r][c]);
                }
            }
        }
    }
    if constexpr (TAIL > 0) {
        constexpr int k0 = FULL * KC;
        float wr[CPT][KC];
#pragma unroll
        for (int c = 0; c < CPT; ++c)
#pragma unroll
            for (int kk = 0; kk < KC; ++kk)
                wr[c][kk] = (kk < TAIL) ? w[(size_t)(k0 + kk) * COUT + o + c * NTH] : 0.f;
#pragma unroll
        for (int r = 0; r < RPT; ++r) {
            const float4* ip = reinterpret_cast<const float4*>(inp + (size_t)r * CINP + k0);
#pragma unroll
            for (int q = 0; q < KC / 4; ++q) {
                float4 v = ip[q];  // padded lanes are zero in LDS
#pragma unroll
                for (int c = 0; c < CPT; ++c) {
                    acc[r][c] = fmaf(v.x, wr[c][4 * q + 0], acc[r][c]);
                    acc[r][c] = fmaf(v.y, wr[c][4 * q + 1], acc[r][c]);
                    acc[r][c] = fmaf(v.z, wr[c][4 * q + 2], acc[r][c]);
                    acc[r][c] = fmaf(v.w, wr[c][4 * q + 3], acc[r][c]);
                }
            }
        }
    }
#pragma unroll
    for (int c = 0; c < CPT; ++c) {
        const int oc = o + c * NTH;
        const float gv = gm[oc], bv = bt[oc];
#pragma unroll
        for (int r = 0; r < RPT; ++r) {
            float v = fmaf(acc[r][c], gv, bv);
            out_lds[(size_t)(rbase + r) * COUT + oc] = fmaxf(v, 0.f);
        }
    }
}

// ===================== Fused SA: gather + MLP + maxpool =====================
// One block per (b, s, half). R=32 rows (neighbors) per block; atomicMax pooling
// (ReLU>=0 so int-compare == float-compare, and output is zero-initialized).
template<int CF, int C0, int C1, int C2, int R>
__global__ __launch_bounds__(NTH) void sa_kernel(
    const float* __restrict__ src_xyz, const float* __restrict__ src_feat,
    const float* __restrict__ centers, const int* __restrict__ nbr,
    const float* __restrict__ w0, const float* __restrict__ g0, const float* __restrict__ b0,
    const float* __restrict__ w1, const float* __restrict__ g1, const float* __restrict__ b1,
    const float* __restrict__ w2, const float* __restrict__ g2, const float* __restrict__ b2,
    float* __restrict__ out_feat, int S, int N)
{
    constexpr int CIN  = 3 + CF;
    constexpr int KC0  = (CIN >= 16) ? 16 : 4;
    constexpr int CINP = ((CIN + KC0 - 1) / KC0) * KC0;
    constexpr int HALVES = 64 / R;
    constexpr int OFF_IN = 0;
    constexpr int OFF_H0 = R * CINP;
    constexpr int OFF_H1 = OFF_H0 + R * C0;
    constexpr bool OVL = (C2 <= CINP + C0);   // h2 may overlap dead in0+h0
    constexpr int OFF_H2 = OVL ? 0 : (OFF_H1 + R * C1);
    constexpr int SMEMF = OVL ? (OFF_H1 + R * C1) : (OFF_H2 + R * C2);
    __shared__ float sm[SMEMF];

    const int tid  = threadIdx.x;
    const int flat = blockIdx.x;
    const int half = flat % HALVES;
    const int bs   = flat / HALVES;
    const int b    = bs / S;
    const int* __restrict__ myidx = nbr + (size_t)bs * 64 + half * R;

    for (int e = tid; e < R * CINP; e += NTH) {
        int r = e / CINP, c = e - r * CINP;
        int pid = myidx[r];
        float v = 0.f;
        if (c < 3)
            v = src_xyz[((size_t)b * N + pid) * 3 + c] - centers[(size_t)bs * 3 + c];
        else if (c < CIN)
            v = src_feat[((size_t)b * N + pid) * CF + (c - 3)];
        sm[OFF_IN + e] = v;
    }
    __syncthreads();
    mlp_layer<CIN, CINP, C0, R, KC0>(w0, g0, b0, sm + OFF_IN, sm + OFF_H0, tid);
    __syncthreads();
    mlp_layer<C0, C0, C1, R, 16>(w1, g1, b1, sm + OFF_H0, sm + OFF_H1, tid);
    __syncthreads();
    mlp_layer<C1, C1, C2, R, 16>(w2, g2, b2, sm + OFF_H1, sm + OFF_H2, tid);
    __syncthreads();
    for (int ch = tid; ch < C2; ch += NTH) {
        float m = 0.f;
#pragma unroll
        for (int r = 0; r < R; ++r) m = fmaxf(m, sm[OFF_H2 + (size_t)r * C2 + ch]);
        atomicMax(reinterpret_cast<int*>(out_feat) + (size_t)bs * C2 + ch, __float_as_int(m));
    }
}

// ===================== SA3 / global head: concat + MLP + maxpool =====================
template<int CF, int C0, int C1, int C2, int R>
__global__ __launch_bounds__(NTH) void global_mlp_kernel(
    const float* __restrict__ xyz, const float* __restrict__ feat,
    const float* __restrict__ w0, const float* __restrict__ g0, const float* __restrict__ b0,
    const float* __restrict__ w1, const float* __restrict__ g1, const float* __restrict__ b1,
    const float* __restrict__ w2, const float* __restrict__ g2, const float* __restrict__ b2,
    float* __restrict__ out, int Np)
{
    constexpr int CIN  = 3 + CF;   // 259
    constexpr int CINP = ((CIN + 15) / 16) * 16;
    constexpr int OFF_IN = 0;
    constexpr int OFF_H0 = R * CINP;
    constexpr int OFF_H1 = OFF_H0 + R * C0;
    constexpr bool OVL = (C2 <= CINP + C0);
    constexpr int OFF_H2 = OVL ? 0 : (OFF_H1 + R * C1);
    constexpr int SMEMF = OVL ? (OFF_H1 + R * C1) : (OFF_H2 + R * C2);
    __shared__ float sm[SMEMF];

    const int tid = threadIdx.x;
    const int chunks = Np / R;
    const int b  = blockIdx.x / chunks;
    const int r0 = (blockIdx.x % chunks) * R;

    for (int e = tid; e < R * CINP; e += NTH) {
        int r = e / CINP, c = e - r * CINP;
        int row = r0 + r;
        float v = 0.f;
        if (c < 3)        v = xyz[((size_t)b * Np + row) * 3 + c];
        else if (c < CIN) v = feat[((size_t)b * Np + row) * CF + (c - 3)];
        sm[OFF_IN + e] = v;
    }
    __syncthreads();
    mlp_layer<CIN, CINP, C0, R, 16>(w0, g0, b0, sm + OFF_IN, sm + OFF_H0, tid);
    __syncthreads();
    mlp_layer<C0, C0, C1, R, 16>(w1, g1, b1, sm + OFF_H0, sm + OFF_H1, tid);
    __syncthreads();
    mlp_layer<C1, C1, C2, R, 16>(w2, g2, b2, sm + OFF_H1, sm + OFF_H2, tid);
    __syncthreads();
    for (int ch = tid; ch < C2; ch += NTH) {
        float m = 0.f;
#pragma unroll
        for (int r = 0; r < R; ++r) m = fmaxf(m, sm[OFF_H2 + (size_t)r * C2 + ch]);
        atomicMax(reinterpret_cast<int*>(out) + (size_t)b * C2 + ch, __float_as_int(m));
    }
}

// ============================== launch ==============================
extern "C" void kernel_launch(void* const* d_in, const int* in_sizes, int n_in,
                              void* d_out, int out_size, void* d_ws, size_t ws_size,
                              hipStream_t stream)
{
    (void)in_sizes; (void)n_in; (void)ws_size;
    const int B = 32, N = 4096;
    const float* pc = (const float*)d_in[0];
    const float* W[27];
    for (int i = 0; i < 27; ++i) W[i] = (const float*)d_in[1 + i];
    float* out = (float*)d_out;

    char* ws = (char*)d_ws;
    size_t off = 0;
    auto take = [&](size_t bytes) {
        void* p = ws + off;
        off += (bytes + 255) & ~(size_t)255;
        return p;
    };
    float* nxyz1 = (float*)take((size_t)B * 512 * 3 * 4);
    int*   idx1  = (int*)  take((size_t)B * 512 * 64 * 4);
    float* feat1 = (float*)take((size_t)B * 512 * 128 * 4);
    float* nxyz2 = (float*)take((size_t)B * 128 * 3 * 4);
    int*   idx2  = (int*)  take((size_t)B * 128 * 64 * 4);
    float* feat2 = (float*)take((size_t)B * 128 * 256 * 4);

    hipMemsetAsync(feat1, 0, (size_t)B * 512 * 128 * 4, stream);
    hipMemsetAsync(feat2, 0, (size_t)B * 128 * 256 * 4, stream);
    hipMemsetAsync(d_out, 0, (size_t)out_size * 4, stream);

    // ---- SA1 ----
    fps_kernel<4096, 512><<<B, NTH, 0, stream>>>(pc, nxyz1);
    ball_query_kernel<<<(B * 512 + 3) / 4, NTH, 0, stream>>>(
        pc, nxyz1, idx1, B * 512, N, 512, (float)(0.2 * 0.2));
    sa_kernel<0, 64, 64, 128, 32><<<B * 512 * 2, NTH, 0, stream>>>(
        pc, nullptr, nxyz1, idx1,
        W[0], W[1], W[2], W[3], W[4], W[5], W[6], W[7], W[8],
        feat1, 512, N);

    // ---- SA2 ----
    fps_kernel<512, 128><<<B, NTH, 0, stream>>>(nxyz1, nxyz2);
    ball_query_kernel<<<(B * 128 + 3) / 4, NTH, 0, stream>>>(
        nxyz1, nxyz2, idx2, B * 128, 512, 128, (float)(0.4 * 0.4));
    sa_kernel<128, 128, 128, 256, 32><<<B * 128 * 2, NTH, 0, stream>>>(
        nxyz1, feat1, nxyz2, idx2,
        W[9], W[10], W[11], W[12], W[13], W[14], W[15], W[16], W[17],
        feat2, 128, 512);

    // ---- SA3 (global head) ----
    global_mlp_kernel<256, 256, 512, 1024, 4><<<B * 32, NTH, 0, stream>>>(
        nxyz2, feat2,
        W[18], W[19], W[20], W[21], W[22], W[23], W[24], W[25], W[26],
        out, 128);
}

// Round 2
// 1387.353 us; speedup vs baseline: 1.8077x; 1.8077x over previous
//
#include <hip/hip_runtime.h>
#include <math.h>

#define NTH 256

using short8 = __attribute__((ext_vector_type(8))) short;
using f32x4  = __attribute__((ext_vector_type(4))) float;

__device__ __forceinline__ unsigned short f2bf(float x) {
    unsigned u = __float_as_uint(x);
    u += 0x7fff + ((u >> 16) & 1);          // round-to-nearest-even
    return (unsigned short)(u >> 16);
}
__device__ __forceinline__ float bf2f(unsigned short h) {
    return __uint_as_float(((unsigned)h) << 16);
}

// ============================= FPS (unchanged, index-exact) =============================
template<int N, int NPOINT>
__global__ __launch_bounds__(NTH) void fps_kernel(
    const float* __restrict__ xyz, float* __restrict__ out_xyz)
{
    constexpr int PT = N / NTH;
    __shared__ float pts[N * 3];
    __shared__ float rv[NTH / 64];
    __shared__ int   ri[NTH / 64];
    __shared__ int   rwin;
    const int tid = threadIdx.x;
    const int b = blockIdx.x;
    const float* src = xyz + (size_t)b * N * 3;
    for (int e = tid; e < N * 3; e += NTH) pts[e] = src[e];
    __syncthreads();

    float px[PT], py[PT], pz[PT], dist[PT];
#pragma unroll
    for (int j = 0; j < PT; ++j) {
        int i = j * NTH + tid;
        px[j] = pts[i * 3 + 0]; py[j] = pts[i * 3 + 1]; pz[j] = pts[i * 3 + 2];
        dist[j] = 1e10f;
    }
    if (tid == 0) {
        out_xyz[(size_t)(b * NPOINT) * 3 + 0] = pts[0];
        out_xyz[(size_t)(b * NPOINT) * 3 + 1] = pts[1];
        out_xyz[(size_t)(b * NPOINT) * 3 + 2] = pts[2];
    }
    int last = 0;
    for (int it = 1; it < NPOINT; ++it) {
        const float lx = pts[last * 3 + 0];
        const float ly = pts[last * 3 + 1];
        const float lz = pts[last * 3 + 2];
        float best = -1.f; int bi = 0;
#pragma unroll
        for (int j = 0; j < PT; ++j) {
            float dx = px[j] - lx, dy = py[j] - ly, dz = pz[j] - lz;
            float d = __fadd_rn(__fadd_rn(__fmul_rn(dx, dx), __fmul_rn(dy, dy)),
                                __fmul_rn(dz, dz));
            float nd = fminf(dist[j], d);
            dist[j] = nd;
            if (nd > best) { best = nd; bi = j * NTH + tid; }
        }
#pragma unroll
        for (int off = 32; off > 0; off >>= 1) {
            float ov = __shfl_down(best, off);
            int   oi = __shfl_down(bi, off);
            if (ov > best || (ov == best && oi < bi)) { best = ov; bi = oi; }
        }
        if ((tid & 63) == 0) { rv[tid >> 6] = best; ri[tid >> 6] = bi; }
        __syncthreads();
        if (tid == 0) {
            float bv = rv[0]; int bx = ri[0];
#pragma unroll
            for (int wv = 1; wv < NTH / 64; ++wv)
                if (rv[wv] > bv || (rv[wv] == bv && ri[wv] < bx)) { bv = rv[wv]; bx = ri[wv]; }
            rwin = bx;
            out_xyz[((size_t)b * NPOINT + it) * 3 + 0] = pts[bx * 3 + 0];
            out_xyz[((size_t)b * NPOINT + it) * 3 + 1] = pts[bx * 3 + 1];
            out_xyz[((size_t)b * NPOINT + it) * 3 + 2] = pts[bx * 3 + 2];
        }
        __syncthreads();
        last = rwin;
    }
}

// ========================== Ball query (unchanged) ==========================
__global__ __launch_bounds__(NTH) void ball_query_kernel(
    const float* __restrict__ xyz, const float* __restrict__ centers,
    int* __restrict__ out, int BS, int N, int S, float r2)
{
    const int wid = blockIdx.x * (NTH / 64) + (threadIdx.x >> 6);
    if (wid >= BS) return;
    const int lane = threadIdx.x & 63;
    const int b = wid / S;
    const float cx = centers[(size_t)wid * 3 + 0];
    const float cy = centers[(size_t)wid * 3 + 1];
    const float cz = centers[(size_t)wid * 3 + 2];
    const float* px = xyz + (size_t)b * N * 3;
    int count = 0, first = -1;
    for (int base = 0; base < N && count < 64; base += 64) {
        int i = base + lane;
        float dx = px[i * 3 + 0] - cx, dy = px[i * 3 + 1] - cy, dz = px[i * 3 + 2] - cz;
        float d2 = __fadd_rn(__fadd_rn(__fmul_rn(dx, dx), __fmul_rn(dy, dy)),
                             __fmul_rn(dz, dz));
        bool inb = d2 < r2;
        unsigned long long m = __ballot(inb);
        if (first < 0 && m) first = base + (__ffsll(m) - 1);
        if (inb) {
            int pos = count + (int)__popcll(m & ((1ull << lane) - 1ull));
            if (pos < 64) out[(size_t)wid * 64 + pos] = i;
        }
        count += (int)__popcll(m);
    }
    int cnt = count > 64 ? 64 : count;
    if (first < 0) first = N - 1;
    if (lane >= cnt) out[(size_t)wid * 64 + lane] = first;
}

// ===================== Weight prep: fp32 [K][N] -> hi/lo bf16 frag layout =====================
// Layout per layer: [KP/8][N][8] bf16 (k zero-padded to KP=ceil32(K)); hi array then lo array.
#define PREP_TOT 813056
__global__ __launch_bounds__(NTH) void prep_weights(
    const float* __restrict__ w0, const float* __restrict__ w1, const float* __restrict__ w2,
    const float* __restrict__ w3, const float* __restrict__ w4, const float* __restrict__ w5,
    const float* __restrict__ w6, const float* __restrict__ w7, const float* __restrict__ w8,
    unsigned short* __restrict__ outw)
{
    const int K_[9]    = {3, 64, 64, 131, 128, 128, 259, 256, 512};
    const int N_[9]    = {64, 64, 128, 128, 128, 256, 256, 512, 1024};
    const int E_[9]    = {2048, 4096, 8192, 20480, 16384, 32768, 73728, 131072, 524288};
    const int base_[9] = {0, 4096, 12288, 28672, 69632, 102400, 167936, 315392, 577536};
    const float* W_[9] = {w0, w1, w2, w3, w4, w5, w6, w7, w8};
    for (int gid = blockIdx.x * NTH + threadIdx.x; gid < PREP_TOT; gid += gridDim.x * NTH) {
        int i = 0, t = gid;
        while (t >= E_[i]) { t -= E_[i]; ++i; }
        const int N = N_[i];
        const int k8 = t / (N * 8);
        const int rem = t - k8 * N * 8;
        const int col = rem >> 3, j = rem & 7;
        const int k = k8 * 8 + j;
        float v = (k < K_[i]) ? W_[i][(size_t)k * N + col] : 0.f;
        unsigned short hi = f2bf(v);
        unsigned short lo = f2bf(v - bf2f(hi));
        outw[base_[i] + t] = hi;
        outw[base_[i] + E_[i] + t] = lo;
    }
}

// ===================== split-bf16 MFMA MLP layer =====================
// X (hi/lo bf16) in LDS, row-stride SX elems. W in frag layout [KP/8][N][8] (hi/lo).
// acc += Ah*Bh + Ah*Bl + Al*Bh  (3x mfma_f32_16x16x32_bf16) -> ~fp32 precision.
// A-frag: row=lane&15, k=(lane>>4)*8+j (ds_read_b128). B-frag mirrored, from global (L2).
// D: col=lane&15, row=(lane>>4)*4+reg.
template<int K, int N, int NSUB, int NOFF, int RTILES, int SX, int SY, bool FINAL>
__device__ __forceinline__ void mfma_layer(
    const unsigned short* __restrict__ whi, const unsigned short* __restrict__ wlo,
    const float* __restrict__ gm, const float* __restrict__ bt,
    const unsigned short* __restrict__ Xhi, const unsigned short* __restrict__ Xlo,
    unsigned short* __restrict__ Yhi, unsigned short* __restrict__ Ylo,
    float* outp, int tid)
{
    constexpr int KP  = (K + 31) & ~31;
    constexpr int KC  = KP / 32;
    constexpr int NT  = NSUB / 16;
    constexpr int NWN = 4 / RTILES;      // waves splitting the N range
    constexpr int NTW = NT / NWN;        // n-tiles per wave
    const int w = tid >> 6, lane = tid & 63;
    const int mt = w % RTILES;
    const int nbase = w / RTILES;
    const int lr = lane & 15, lg = lane >> 4;

    f32x4 acc[NTW];
#pragma unroll
    for (int t = 0; t < NTW; ++t) acc[t] = f32x4{0.f, 0.f, 0.f, 0.f};

    const unsigned short* xh = Xhi + (mt * 16 + lr) * SX + lg * 8;
    const unsigned short* xl = Xlo + (mt * 16 + lr) * SX + lg * 8;

    for (int kc = 0; kc < KC; ++kc) {
        short8 ah = *reinterpret_cast<const short8*>(xh + kc * 32);
        short8 al = *reinterpret_cast<const short8*>(xl + kc * 32);
        const size_t krow = (size_t)(kc * 4 + lg) * N * 8;
#pragma unroll
        for (int t = 0; t < NTW; ++t) {
            const int col = NOFF + (nbase + t * NWN) * 16 + lr;
            short8 bh = *reinterpret_cast<const short8*>(whi + krow + (size_t)col * 8);
            short8 bl = *reinterpret_cast<const short8*>(wlo + krow + (size_t)col * 8);
            acc[t] = __builtin_amdgcn_mfma_f32_16x16x32_bf16(ah, bh, acc[t], 0, 0, 0);
            acc[t] = __builtin_amdgcn_mfma_f32_16x16x32_bf16(ah, bl, acc[t], 0, 0, 0);
            acc[t] = __builtin_amdgcn_mfma_f32_16x16x32_bf16(al, bh, acc[t], 0, 0, 0);
        }
    }
#pragma unroll
    for (int t = 0; t < NTW; ++t) {
        const int col = NOFF + (nbase + t * NWN) * 16 + lr;
        const float gv = gm[col], bv = bt[col];
        if constexpr (FINAL) {
            float m = 0.f;
#pragma unroll
            for (int r = 0; r < 4; ++r)
                m = fmaxf(m, fmaxf(fmaf(acc[t][r], gv, bv), 0.f));
            m = fmaxf(m, __shfl_xor(m, 16));
            m = fmaxf(m, __shfl_xor(m, 32));
            if (lg == 0)
                atomicMax(reinterpret_cast<int*>(outp) + col, __float_as_int(m));
        } else {
#pragma unroll
            for (int r = 0; r < 4; ++r) {
                float v = fmaxf(fmaf(acc[t][r], gv, bv), 0.f);
                unsigned short hi = f2bf(v);
                unsigned short lo = f2bf(v - bf2f(hi));
                const int row = mt * 16 + lg * 4 + r;
                Yhi[row * SY + col] = hi;
                Ylo[row * SY + col] = lo;
            }
        }
    }
}

// ===================== Fused SA: gather + 3x MFMA-MLP + maxpool =====================
// R rows (neighbors) per block; atomicMax pooling into zero-initialized out_feat.
template<int CF, int C0, int C1, int C2, int R>
__global__ __launch_bounds__(NTH) void sa_mfma(
    const float* __restrict__ src_xyz, const float* __restrict__ src_feat,
    const float* __restrict__ centers, const int* __restrict__ nbr,
    const unsigned short* __restrict__ w0h, const unsigned short* __restrict__ w0l,
    const unsigned short* __restrict__ w1h, const unsigned short* __restrict__ w1l,
    const unsigned short* __restrict__ w2h, const unsigned short* __restrict__ w2l,
    const float* __restrict__ g0, const float* __restrict__ b0,
    const float* __restrict__ g1, const float* __restrict__ b1,
    const float* __restrict__ g2, const float* __restrict__ b2,
    float* __restrict__ out_feat, int S, int N)
{
    constexpr int CIN = 3 + CF;
    constexpr int KP0 = (CIN + 31) & ~31;
    constexpr int SX = KP0 + 8, SY1 = C0 + 8, SY2 = C1 + 8;   // +8: 2-way-max bank aliasing
    constexpr int RT = R / 16;
    constexpr int HALVES = 64 / R;
    constexpr int OFF_Y1 = 0;
    constexpr int OFF_X  = 2 * R * SY1;          // X region; Y2 reuses it (X dead by then)
    constexpr int XSZ = 2 * R * SX, Y2SZ = 2 * R * SY2;
    constexpr int TOT = OFF_X + (XSZ > Y2SZ ? XSZ : Y2SZ);
    __shared__ __align__(16) unsigned short sm[TOT];

    const int tid  = threadIdx.x;
    const int flat = blockIdx.x;
    const int half = flat % HALVES;
    const int bs   = flat / HALVES;
    const int b    = bs / S;
    const int* __restrict__ myidx = nbr + (size_t)bs * 64 + half * R;

    unsigned short* Xhi = sm + OFF_X;   unsigned short* Xlo = Xhi + R * SX;
    unsigned short* Y1h = sm + OFF_Y1;  unsigned short* Y1l = Y1h + R * SY1;
    unsigned short* Y2h = sm + OFF_X;   unsigned short* Y2l = Y2h + R * SY2;

    const float cx = centers[(size_t)bs * 3 + 0];
    const float cy = centers[(size_t)bs * 3 + 1];
    const float cz = centers[(size_t)bs * 3 + 2];
    for (int e = tid; e < R * KP0; e += NTH) {
        const int r = e / KP0, c = e - (e / KP0) * KP0;
        const int pid = myidx[r];
        float v = 0.f;
        if (c < 3) {
            float p = src_xyz[((size_t)b * N + pid) * 3 + c];
            v = p - (c == 0 ? cx : (c == 1 ? cy : cz));
        } else if constexpr (CF > 0) {
            if (c < CIN) v = src_feat[((size_t)b * N + pid) * CF + (c - 3)];
        }
        unsigned short hi = f2bf(v);
        unsigned short lo = f2bf(v - bf2f(hi));
        Xhi[r * SX + c] = hi; Xlo[r * SX + c] = lo;
    }
    __syncthreads();
    mfma_layer<CIN, C0, C0, 0, RT, SX, SY1, false>(w0h, w0l, g0, b0, Xhi, Xlo, Y1h, Y1l, nullptr, tid);
    __syncthreads();
    mfma_layer<C0, C1, C1, 0, RT, SY1, SY2, false>(w1h, w1l, g1, b1, Y1h, Y1l, Y2h, Y2l, nullptr, tid);
    __syncthreads();
    mfma_layer<C1, C2, C2, 0, RT, SY2, 0, true>(w2h, w2l, g2, b2, Y2h, Y2l, nullptr, nullptr,
                                                out_feat + (size_t)bs * C2, tid);
}

// ===================== Head: concat(xyz,feat) + 3x MFMA-MLP + global maxpool =====================
template<int CF, int C0, int C1, int C2>
__global__ __launch_bounds__(NTH) void head_mfma(
    const float* __restrict__ xyz, const float* __restrict__ feat,
    const unsigned short* __restrict__ w0h, const unsigned short* __restrict__ w0l,
    const unsigned short* __restrict__ w1h, const unsigned short* __restrict__ w1l,
    const unsigned short* __restrict__ w2h, const unsigned short* __restrict__ w2l,
    const float* __restrict__ g0, const float* __restrict__ b0,
    const float* __restrict__ g1, const float* __restrict__ b1,
    const float* __restrict__ g2, const float* __restrict__ b2,
    float* __restrict__ out, int Np)
{
    constexpr int R = 16;
    constexpr int CIN = 3 + CF;                  // 259
    constexpr int KP0 = (CIN + 31) & ~31;        // 288
    constexpr int SX = KP0 + 8, SY1 = C0 + 8, SY2 = C1 + 8;
    constexpr int OFF_Y1 = 0;
    constexpr int OFF_X  = 2 * R * SY1;
    constexpr int XSZ = 2 * R * SX, Y2SZ = 2 * R * SY2;
    constexpr int TOT = OFF_X + (XSZ > Y2SZ ? XSZ : Y2SZ);
    __shared__ __align__(16) unsigned short sm[TOT];

    const int tid = threadIdx.x;
    const int chunks = Np / R;
    const int b  = blockIdx.x / chunks;
    const int r0 = (blockIdx.x % chunks) * R;

    unsigned short* Xhi = sm + OFF_X;   unsigned short* Xlo = Xhi + R * SX;
    unsigned short* Y1h = sm + OFF_Y1;  unsigned short* Y1l = Y1h + R * SY1;
    unsigned short* Y2h = sm + OFF_X;   unsigned short* Y2l = Y2h + R * SY2;

    for (int e = tid; e < R * KP0; e += NTH) {
        const int r = e / KP0, c = e - (e / KP0) * KP0;
        const int row = r0 + r;
        float v = 0.f;
        if (c < 3)        v = xyz[((size_t)b * Np + row) * 3 + c];
        else if (c < CIN) v = feat[((size_t)b * Np + row) * CF + (c - 3)];
        unsigned short hi = f2bf(v);
        unsigned short lo = f2bf(v - bf2f(hi));
        Xhi[r * SX + c] = hi; Xlo[r * SX + c] = lo;
    }
    __syncthreads();
    mfma_layer<CIN, C0, C0, 0, 1, SX, SY1, false>(w0h, w0l, g0, b0, Xhi, Xlo, Y1h, Y1l, nullptr, tid);
    __syncthreads();
    mfma_layer<C0, C1, C1, 0, 1, SY1, SY2, false>(w1h, w1l, g1, b1, Y1h, Y1l, Y2h, Y2l, nullptr, tid);
    __syncthreads();
    float* op = out + (size_t)b * C2;
    mfma_layer<C1, C2, C2 / 2, 0,      1, SY2, 0, true>(w2h, w2l, g2, b2, Y2h, Y2l, nullptr, nullptr, op, tid);
    mfma_layer<C1, C2, C2 / 2, C2 / 2, 1, SY2, 0, true>(w2h, w2l, g2, b2, Y2h, Y2l, nullptr, nullptr, op, tid);
}

// ============================== launch ==============================
extern "C" void kernel_launch(void* const* d_in, const int* in_sizes, int n_in,
                              void* d_out, int out_size, void* d_ws, size_t ws_size,
                              hipStream_t stream)
{
    (void)in_sizes; (void)n_in; (void)ws_size;
    const int B = 32, N = 4096;
    const float* pc = (const float*)d_in[0];
    const float* W[27];
    for (int i = 0; i < 27; ++i) W[i] = (const float*)d_in[1 + i];
    float* out = (float*)d_out;

    char* ws = (char*)d_ws;
    size_t off = 0;
    auto take = [&](size_t bytes) {
        void* p = ws + off;
        off += (bytes + 255) & ~(size_t)255;
        return p;
    };
    float* nxyz1 = (float*)take((size_t)B * 512 * 3 * 4);
    int*   idx1  = (int*)  take((size_t)B * 512 * 64 * 4);
    float* feat1 = (float*)take((size_t)B * 512 * 128 * 4);
    float* nxyz2 = (float*)take((size_t)B * 128 * 3 * 4);
    int*   idx2  = (int*)  take((size_t)B * 128 * 64 * 4);
    float* feat2 = (float*)take((size_t)B * 128 * 256 * 4);
    unsigned short* wf = (unsigned short*)take((size_t)1626112 * 2);  // 9-layer hi/lo frag weights

    // per-layer frag offsets (elems): base_i, hi at base, lo at base+E
    const int E_[9]    = {2048, 4096, 8192, 20480, 16384, 32768, 73728, 131072, 524288};
    const int base_[9] = {0, 4096, 12288, 28672, 69632, 102400, 167936, 315392, 577536};
    const unsigned short* wh[9]; const unsigned short* wl[9];
    for (int i = 0; i < 9; ++i) { wh[i] = wf + base_[i]; wl[i] = wf + base_[i] + E_[i]; }

    hipMemsetAsync(feat1, 0, (size_t)B * 512 * 128 * 4, stream);
    hipMemsetAsync(feat2, 0, (size_t)B * 128 * 256 * 4, stream);
    hipMemsetAsync(d_out, 0, (size_t)out_size * 4, stream);

    prep_weights<<<(PREP_TOT + NTH - 1) / NTH, NTH, 0, stream>>>(
        W[0], W[3], W[6], W[9], W[12], W[15], W[18], W[21], W[24], wf);

    // ---- SA1 ----
    fps_kernel<4096, 512><<<B, NTH, 0, stream>>>(pc, nxyz1);
    ball_query_kernel<<<(B * 512 + 3) / 4, NTH, 0, stream>>>(
        pc, nxyz1, idx1, B * 512, N, 512, (float)(0.2 * 0.2));
    sa_mfma<0, 64, 64, 128, 64><<<B * 512, NTH, 0, stream>>>(
        pc, nullptr, nxyz1, idx1,
        wh[0], wl[0], wh[1], wl[1], wh[2], wl[2],
        W[1], W[2], W[4], W[5], W[7], W[8],
        feat1, 512, N);

    // ---- SA2 ----
    fps_kernel<512, 128><<<B, NTH, 0, stream>>>(nxyz1, nxyz2);
    ball_query_kernel<<<(B * 128 + 3) / 4, NTH, 0, stream>>>(
        nxyz1, nxyz2, idx2, B * 128, 512, 128, (float)(0.4 * 0.4));
    sa_mfma<128, 128, 128, 256, 32><<<B * 128 * 2, NTH, 0, stream>>>(
        nxyz1, feat1, nxyz2, idx2,
        wh[3], wl[3], wh[4], wl[4], wh[5], wl[5],
        W[10], W[11], W[13], W[14], W[16], W[17],
        feat2, 128, 512);

    // ---- SA3 / global head ----
    head_mfma<256, 256, 512, 1024><<<B * 8, NTH, 0, stream>>>(
        nxyz2, feat2,
        wh[6], wl[6], wh[7], wl[7], wh[8], wl[8],
        W[19], W[20], W[22], W[23], W[25], W[26],
        out, 128);
}

// Round 3
// 1138.465 us; speedup vs baseline: 2.2029x; 1.2186x over previous
//
#include <hip/hip_runtime.h>
#include <math.h>

#define NTH 256

using short8 = __attribute__((ext_vector_type(8))) short;
using f32x4  = __attribute__((ext_vector_type(4))) float;

__device__ __forceinline__ unsigned short f2bf(float x) {
    unsigned u = __float_as_uint(x);
    u += 0x7fff + ((u >> 16) & 1);          // round-to-nearest-even
    return (unsigned short)(u >> 16);
}
__device__ __forceinline__ float bf2f(unsigned short h) {
    return __uint_as_float(((unsigned)h) << 16);
}

// ============================= FPS =============================
// Packed u64 key (dist-bits<<32 | ~idx): max == (max dist, lowest idx) — matches
// numpy argmax first-occurrence. One barrier/iter via parity-buffered wave winners.
// Distance arithmetic is op-identical to reference ((dx*dx+dy*dy)+dz*dz, RN, no fma).
template<int N, int NPOINT, int NTHR>
__device__ __forceinline__ void fps_body(
    const float* __restrict__ xyz, float* __restrict__ out_xyz, int b,
    float* __restrict__ pts, unsigned long long* __restrict__ wkey /* 2*NW */)
{
    constexpr int PT = N / NTHR;
    constexpr int NW = NTHR / 64;
    const int tid  = threadIdx.x;
    const int lane = tid & 63;
    const int w    = tid >> 6;
    const float* src = xyz + (size_t)b * N * 3;
    for (int e = tid; e < N * 3; e += NTHR) pts[e] = src[e];
    __syncthreads();

    float px[PT], py[PT], pz[PT], dist[PT];
    unsigned ic[PT];
#pragma unroll
    for (int j = 0; j < PT; ++j) {
        int i = j * NTHR + tid;
        px[j] = pts[i * 3 + 0]; py[j] = pts[i * 3 + 1]; pz[j] = pts[i * 3 + 2];
        dist[j] = 1e10f;
        ic[j] = ~(unsigned)i;
    }
    if (tid == 0) {
        out_xyz[(size_t)b * NPOINT * 3 + 0] = pts[0];
        out_xyz[(size_t)b * NPOINT * 3 + 1] = pts[1];
        out_xyz[(size_t)b * NPOINT * 3 + 2] = pts[2];
    }
    int last = 0;
    for (int it = 1; it < NPOINT; ++it) {
        const float lx = pts[last * 3 + 0];
        const float ly = pts[last * 3 + 1];
        const float lz = pts[last * 3 + 2];
        unsigned long long best = 0ull;
#pragma unroll
        for (int j = 0; j < PT; ++j) {
            float dx = px[j] - lx, dy = py[j] - ly, dz = pz[j] - lz;
            float d = __fadd_rn(__fadd_rn(__fmul_rn(dx, dx), __fmul_rn(dy, dy)),
                                __fmul_rn(dz, dz));
            float nd = fminf(dist[j], d);
            dist[j] = nd;
            unsigned long long key =
                ((unsigned long long)__float_as_uint(nd) << 32) | (unsigned long long)ic[j];
            best = (key > best) ? key : best;
        }
#pragma unroll
        for (int off = 32; off > 0; off >>= 1) {
            unsigned long long o = __shfl_xor(best, off);
            best = (o > best) ? o : best;
        }
        if (lane == 0) wkey[(it & 1) * NW + w] = best;
        __syncthreads();
#pragma unroll
        for (int v = 0; v < NW; ++v) {
            unsigned long long o = wkey[(it & 1) * NW + v];
            best = (o > best) ? o : best;
        }
        last = (int)(~(unsigned)best);
        if (tid == 0) {
            out_xyz[((size_t)b * NPOINT + it) * 3 + 0] = pts[last * 3 + 0];
            out_xyz[((size_t)b * NPOINT + it) * 3 + 1] = pts[last * 3 + 1];
            out_xyz[((size_t)b * NPOINT + it) * 3 + 2] = pts[last * 3 + 2];
        }
    }
}

template<int N, int NPOINT, int NTHR>
__global__ __launch_bounds__(NTHR) void fps_kernel(
    const float* __restrict__ xyz, float* __restrict__ out_xyz)
{
    __shared__ float pts[N * 3];
    __shared__ unsigned long long wkey[2 * (NTHR / 64)];
    fps_body<N, NPOINT, NTHR>(xyz, out_xyz, blockIdx.x, pts, wkey);
}

// ========================== Ball query (unchanged) ==========================
__global__ __launch_bounds__(NTH) void ball_query_kernel(
    const float* __restrict__ xyz, const float* __restrict__ centers,
    int* __restrict__ out, int BS, int N, int S, float r2)
{
    const int wid = blockIdx.x * (NTH / 64) + (threadIdx.x >> 6);
    if (wid >= BS) return;
    const int lane = threadIdx.x & 63;
    const int b = wid / S;
    const float cx = centers[(size_t)wid * 3 + 0];
    const float cy = centers[(size_t)wid * 3 + 1];
    const float cz = centers[(size_t)wid * 3 + 2];
    const float* px = xyz + (size_t)b * N * 3;
    int count = 0, first = -1;
    for (int base = 0; base < N && count < 64; base += 64) {
        int i = base + lane;
        float dx = px[i * 3 + 0] - cx, dy = px[i * 3 + 1] - cy, dz = px[i * 3 + 2] - cz;
        float d2 = __fadd_rn(__fadd_rn(__fmul_rn(dx, dx), __fmul_rn(dy, dy)),
                             __fmul_rn(dz, dz));
        bool inb = d2 < r2;
        unsigned long long m = __ballot(inb);
        if (first < 0 && m) first = base + (__ffsll(m) - 1);
        if (inb) {
            int pos = count + (int)__popcll(m & ((1ull << lane) - 1ull));
            if (pos < 64) out[(size_t)wid * 64 + pos] = i;
        }
        count += (int)__popcll(m);
    }
    int cnt = count > 64 ? 64 : count;
    if (first < 0) first = N - 1;
    if (lane >= cnt) out[(size_t)wid * 64 + lane] = first;
}

// ===================== Weight prep (unchanged) =====================
#define PREP_TOT 813056
__global__ __launch_bounds__(NTH) void prep_weights(
    const float* __restrict__ w0, const float* __restrict__ w1, const float* __restrict__ w2,
    const float* __restrict__ w3, const float* __restrict__ w4, const float* __restrict__ w5,
    const float* __restrict__ w6, const float* __restrict__ w7, const float* __restrict__ w8,
    unsigned short* __restrict__ outw)
{
    const int K_[9]    = {3, 64, 64, 131, 128, 128, 259, 256, 512};
    const int N_[9]    = {64, 64, 128, 128, 128, 256, 256, 512, 1024};
    const int E_[9]    = {2048, 4096, 8192, 20480, 16384, 32768, 73728, 131072, 524288};
    const int base_[9] = {0, 4096, 12288, 28672, 69632, 102400, 167936, 315392, 577536};
    const float* W_[9] = {w0, w1, w2, w3, w4, w5, w6, w7, w8};
    for (int gid = blockIdx.x * NTH + threadIdx.x; gid < PREP_TOT; gid += gridDim.x * NTH) {
        int i = 0, t = gid;
        while (t >= E_[i]) { t -= E_[i]; ++i; }
        const int N = N_[i];
        const int k8 = t / (N * 8);
        const int rem = t - k8 * N * 8;
        const int col = rem >> 3, j = rem & 7;
        const int k = k8 * 8 + j;
        float v = (k < K_[i]) ? W_[i][(size_t)k * N + col] : 0.f;
        unsigned short hi = f2bf(v);
        unsigned short lo = f2bf(v - bf2f(hi));
        outw[base_[i] + t] = hi;
        outw[base_[i] + E_[i] + t] = lo;
    }
}

// ===================== split-bf16 MFMA MLP layer (unchanged) =====================
template<int K, int N, int NSUB, int NOFF, int RTILES, int SX, int SY, bool FINAL>
__device__ __forceinline__ void mfma_layer(
    const unsigned short* __restrict__ whi, const unsigned short* __restrict__ wlo,
    const float* __restrict__ gm, const float* __restrict__ bt,
    const unsigned short* __restrict__ Xhi, const unsigned short* __restrict__ Xlo,
    unsigned short* __restrict__ Yhi, unsigned short* __restrict__ Ylo,
    float* outp, int tid)
{
    constexpr int KP  = (K + 31) & ~31;
    constexpr int KC  = KP / 32;
    constexpr int NT  = NSUB / 16;
    constexpr int NWN = 4 / RTILES;
    constexpr int NTW = NT / NWN;
    const int w = tid >> 6, lane = tid & 63;
    const int mt = w % RTILES;
    const int nbase = w / RTILES;
    const int lr = lane & 15, lg = lane >> 4;

    f32x4 acc[NTW];
#pragma unroll
    for (int t = 0; t < NTW; ++t) acc[t] = f32x4{0.f, 0.f, 0.f, 0.f};

    const unsigned short* xh = Xhi + (mt * 16 + lr) * SX + lg * 8;
    const unsigned short* xl = Xlo + (mt * 16 + lr) * SX + lg * 8;

    for (int kc = 0; kc < KC; ++kc) {
        short8 ah = *reinterpret_cast<const short8*>(xh + kc * 32);
        short8 al = *reinterpret_cast<const short8*>(xl + kc * 32);
        const size_t krow = (size_t)(kc * 4 + lg) * N * 8;
#pragma unroll
        for (int t = 0; t < NTW; ++t) {
            const int col = NOFF + (nbase + t * NWN) * 16 + lr;
            short8 bh = *reinterpret_cast<const short8*>(whi + krow + (size_t)col * 8);
            short8 bl = *reinterpret_cast<const short8*>(wlo + krow + (size_t)col * 8);
            acc[t] = __builtin_amdgcn_mfma_f32_16x16x32_bf16(ah, bh, acc[t], 0, 0, 0);
            acc[t] = __builtin_amdgcn_mfma_f32_16x16x32_bf16(ah, bl, acc[t], 0, 0, 0);
            acc[t] = __builtin_amdgcn_mfma_f32_16x16x32_bf16(al, bh, acc[t], 0, 0, 0);
        }
    }
#pragma unroll
    for (int t = 0; t < NTW; ++t) {
        const int col = NOFF + (nbase + t * NWN) * 16 + lr;
        const float gv = gm[col], bv = bt[col];
        if constexpr (FINAL) {
            float m = 0.f;
#pragma unroll
            for (int r = 0; r < 4; ++r)
                m = fmaxf(m, fmaxf(fmaf(acc[t][r], gv, bv), 0.f));
            m = fmaxf(m, __shfl_xor(m, 16));
            m = fmaxf(m, __shfl_xor(m, 32));
            if (lg == 0)
                atomicMax(reinterpret_cast<int*>(outp) + col, __float_as_int(m));
        } else {
#pragma unroll
            for (int r = 0; r < 4; ++r) {
                float v = fmaxf(fmaf(acc[t][r], gv, bv), 0.f);
                unsigned short hi = f2bf(v);
                unsigned short lo = f2bf(v - bf2f(hi));
                const int row = mt * 16 + lg * 4 + r;
                Yhi[row * SY + col] = hi;
                Ylo[row * SY + col] = lo;
            }
        }
    }
}

// ===================== SA body: gather + 3x MFMA-MLP + maxpool =====================
template<int CF, int C0, int C1, int C2, int R>
struct SaCfg {
    static constexpr int CIN = 3 + CF;
    static constexpr int KP0 = (CIN + 31) & ~31;
    static constexpr int SX = KP0 + 8, SY1 = C0 + 8, SY2 = C1 + 8;
    static constexpr int RT = R / 16;
    static constexpr int HALVES = 64 / R;
    static constexpr int OFF_Y1 = 0;
    static constexpr int OFF_X = 2 * R * SY1;
    static constexpr int XSZ = 2 * R * SX, Y2SZ = 2 * R * SY2;
    static constexpr int TOT = OFF_X + (XSZ > Y2SZ ? XSZ : Y2SZ);
};

template<int CF, int C0, int C1, int C2, int R>
__device__ __forceinline__ void sa_body(
    unsigned short* __restrict__ sm, int flat,
    const float* __restrict__ src_xyz, const float* __restrict__ src_feat,
    const float* __restrict__ centers, const int* __restrict__ nbr,
    const unsigned short* __restrict__ w0h, const unsigned short* __restrict__ w0l,
    const unsigned short* __restrict__ w1h, const unsigned short* __restrict__ w1l,
    const unsigned short* __restrict__ w2h, const unsigned short* __restrict__ w2l,
    const float* __restrict__ g0, const float* __restrict__ b0,
    const float* __restrict__ g1, const float* __restrict__ b1,
    const float* __restrict__ g2, const float* __restrict__ b2,
    float* __restrict__ out_feat, int S, int N)
{
    using C = SaCfg<CF, C0, C1, C2, R>;
    const int tid  = threadIdx.x;
    const int half = flat % C::HALVES;
    const int bs   = flat / C::HALVES;
    const int b    = bs / S;
    const int* __restrict__ myidx = nbr + (size_t)bs * 64 + half * R;

    unsigned short* Xhi = sm + C::OFF_X;    unsigned short* Xlo = Xhi + R * C::SX;
    unsigned short* Y1h = sm + C::OFF_Y1;   unsigned short* Y1l = Y1h + R * C::SY1;
    unsigned short* Y2h = sm + C::OFF_X;    unsigned short* Y2l = Y2h + R * C::SY2;

    const float cx = centers[(size_t)bs * 3 + 0];
    const float cy = centers[(size_t)bs * 3 + 1];
    const float cz = centers[(size_t)bs * 3 + 2];
    for (int e = tid; e < R * C::KP0; e += NTH) {
        const int r = e / C::KP0, c = e - (e / C::KP0) * C::KP0;
        const int pid = myidx[r];
        float v = 0.f;
        if (c < 3) {
            float p = src_xyz[((size_t)b * N + pid) * 3 + c];
            v = p - (c == 0 ? cx : (c == 1 ? cy : cz));
        } else if constexpr (CF > 0) {
            if (c < C::CIN) v = src_feat[((size_t)b * N + pid) * CF + (c - 3)];
        }
        unsigned short hi = f2bf(v);
        unsigned short lo = f2bf(v - bf2f(hi));
        Xhi[r * C::SX + c] = hi; Xlo[r * C::SX + c] = lo;
    }
    __syncthreads();
    mfma_layer<C::CIN, C0, C0, 0, C::RT, C::SX, C::SY1, false>(
        w0h, w0l, g0, b0, Xhi, Xlo, Y1h, Y1l, nullptr, tid);
    __syncthreads();
    mfma_layer<C0, C1, C1, 0, C::RT, C::SY1, C::SY2, false>(
        w1h, w1l, g1, b1, Y1h, Y1l, Y2h, Y2l, nullptr, tid);
    __syncthreads();
    mfma_layer<C1, C2, C2, 0, C::RT, C::SY2, 0, true>(
        w2h, w2l, g2, b2, Y2h, Y2l, nullptr, nullptr,
        out_feat + (size_t)bs * C2, tid);
}

template<int CF, int C0, int C1, int C2, int R>
__global__ __launch_bounds__(NTH) void sa_mfma(
    const float* __restrict__ src_xyz, const float* __restrict__ src_feat,
    const float* __restrict__ centers, const int* __restrict__ nbr,
    const unsigned short* __restrict__ w0h, const unsigned short* __restrict__ w0l,
    const unsigned short* __restrict__ w1h, const unsigned short* __restrict__ w1l,
    const unsigned short* __restrict__ w2h, const unsigned short* __restrict__ w2l,
    const float* __restrict__ g0, const float* __restrict__ b0,
    const float* __restrict__ g1, const float* __restrict__ b1,
    const float* __restrict__ g2, const float* __restrict__ b2,
    float* __restrict__ out_feat, int S, int N)
{
    __shared__ __align__(16) unsigned short sm[SaCfg<CF, C0, C1, C2, R>::TOT];
    sa_body<CF, C0, C1, C2, R>(sm, blockIdx.x, src_xyz, src_feat, centers, nbr,
                               w0h, w0l, w1h, w1l, w2h, w2l,
                               g0, b0, g1, b1, g2, b2, out_feat, S, N);
}

// ===== Merged: SA1 (blocks < NSA) + FPS2 (blocks >= NSA), FPS2 hides under SA1 =====
template<int CF, int C0, int C1, int C2, int R, int N2, int NP2>
__global__ __launch_bounds__(NTH) void sa1_fps2(
    const float* __restrict__ src_xyz, const float* __restrict__ src_feat,
    const float* __restrict__ centers, const int* __restrict__ nbr,
    const unsigned short* __restrict__ w0h, const unsigned short* __restrict__ w0l,
    const unsigned short* __restrict__ w1h, const unsigned short* __restrict__ w1l,
    const unsigned short* __restrict__ w2h, const unsigned short* __restrict__ w2l,
    const float* __restrict__ g0, const float* __restrict__ b0,
    const float* __restrict__ g1, const float* __restrict__ b1,
    const float* __restrict__ g2, const float* __restrict__ b2,
    float* __restrict__ out_feat, int S, int N,
    const float* __restrict__ fps_in, float* __restrict__ fps_out, int NSA)
{
    constexpr size_t SAB = (size_t)SaCfg<CF, C0, C1, C2, R>::TOT * 2;
    constexpr size_t FPB = (size_t)N2 * 3 * 4 + 2 * (NTH / 64) * 8;
    constexpr size_t BYTES = SAB > FPB ? SAB : FPB;
    __shared__ __align__(16) char smraw[BYTES];
    if ((int)blockIdx.x < NSA) {
        sa_body<CF, C0, C1, C2, R>((unsigned short*)smraw, blockIdx.x,
                                   src_xyz, src_feat, centers, nbr,
                                   w0h, w0l, w1h, w1l, w2h, w2l,
                                   g0, b0, g1, b1, g2, b2, out_feat, S, N);
    } else {
        fps_body<N2, NP2, NTH>(fps_in, fps_out, blockIdx.x - NSA,
                               (float*)smraw,
                               (unsigned long long*)(smraw + (size_t)N2 * 3 * 4));
    }
}

// ===================== Head (unchanged) =====================
template<int CF, int C0, int C1, int C2>
__global__ __launch_bounds__(NTH) void head_mfma(
    const float* __restrict__ xyz, const float* __restrict__ feat,
    const unsigned short* __restrict__ w0h, const unsigned short* __restrict__ w0l,
    const unsigned short* __restrict__ w1h, const unsigned short* __restrict__ w1l,
    const unsigned short* __restrict__ w2h, const unsigned short* __restrict__ w2l,
    const float* __restrict__ g0, const float* __restrict__ b0,
    const float* __restrict__ g1, const float* __restrict__ b1,
    const float* __restrict__ g2, const float* __restrict__ b2,
    float* __restrict__ out, int Np)
{
    constexpr int R = 16;
    constexpr int CIN = 3 + CF;
    constexpr int KP0 = (CIN + 31) & ~31;
    constexpr int SX = KP0 + 8, SY1 = C0 + 8, SY2 = C1 + 8;
    constexpr int OFF_Y1 = 0;
    constexpr int OFF_X  = 2 * R * SY1;
    constexpr int XSZ = 2 * R * SX, Y2SZ = 2 * R * SY2;
    constexpr int TOT = OFF_X + (XSZ > Y2SZ ? XSZ : Y2SZ);
    __shared__ __align__(16) unsigned short sm[TOT];

    const int tid = threadIdx.x;
    const int chunks = Np / R;
    const int b  = blockIdx.x / chunks;
    const int r0 = (blockIdx.x % chunks) * R;

    unsigned short* Xhi = sm + OFF_X;   unsigned short* Xlo = Xhi + R * SX;
    unsigned short* Y1h = sm + OFF_Y1;  unsigned short* Y1l = Y1h + R * SY1;
    unsigned short* Y2h = sm + OFF_X;   unsigned short* Y2l = Y2h + R * SY2;

    for (int e = tid; e < R * KP0; e += NTH) {
        const int r = e / KP0, c = e - (e / KP0) * KP0;
        const int row = r0 + r;
        float v = 0.f;
        if (c < 3)        v = xyz[((size_t)b * Np + row) * 3 + c];
        else if (c < CIN) v = feat[((size_t)b * Np + row) * CF + (c - 3)];
        unsigned short hi = f2bf(v);
        unsigned short lo = f2bf(v - bf2f(hi));
        Xhi[r * SX + c] = hi; Xlo[r * SX + c] = lo;
    }
    __syncthreads();
    mfma_layer<CIN, C0, C0, 0, 1, SX, SY1, false>(w0h, w0l, g0, b0, Xhi, Xlo, Y1h, Y1l, nullptr, tid);
    __syncthreads();
    mfma_layer<C0, C1, C1, 0, 1, SY1, SY2, false>(w1h, w1l, g1, b1, Y1h, Y1l, Y2h, Y2l, nullptr, tid);
    __syncthreads();
    float* op = out + (size_t)b * C2;
    mfma_layer<C1, C2, C2 / 2, 0,      1, SY2, 0, true>(w2h, w2l, g2, b2, Y2h, Y2l, nullptr, nullptr, op, tid);
    mfma_layer<C1, C2, C2 / 2, C2 / 2, 1, SY2, 0, true>(w2h, w2l, g2, b2, Y2h, Y2l, nullptr, nullptr, op, tid);
}

// ============================== launch ==============================
extern "C" void kernel_launch(void* const* d_in, const int* in_sizes, int n_in,
                              void* d_out, int out_size, void* d_ws, size_t ws_size,
                              hipStream_t stream)
{
    (void)in_sizes; (void)n_in; (void)ws_size;
    const int B = 32, N = 4096;
    const float* pc = (const float*)d_in[0];
    const float* W[27];
    for (int i = 0; i < 27; ++i) W[i] = (const float*)d_in[1 + i];
    float* out = (float*)d_out;

    char* ws = (char*)d_ws;
    size_t off = 0;
    auto take = [&](size_t bytes) {
        void* p = ws + off;
        off += (bytes + 255) & ~(size_t)255;
        return p;
    };
    float* nxyz1 = (float*)take((size_t)B * 512 * 3 * 4);
    int*   idx1  = (int*)  take((size_t)B * 512 * 64 * 4);
    float* feat1 = (float*)take((size_t)B * 512 * 128 * 4);
    float* nxyz2 = (float*)take((size_t)B * 128 * 3 * 4);
    int*   idx2  = (int*)  take((size_t)B * 128 * 64 * 4);
    float* feat2 = (float*)take((size_t)B * 128 * 256 * 4);
    unsigned short* wf = (unsigned short*)take((size_t)1626112 * 2);

    const int E_[9]    = {2048, 4096, 8192, 20480, 16384, 32768, 73728, 131072, 524288};
    const int base_[9] = {0, 4096, 12288, 28672, 69632, 102400, 167936, 315392, 577536};
    const unsigned short* wh[9]; const unsigned short* wl[9];
    for (int i = 0; i < 9; ++i) { wh[i] = wf + base_[i]; wl[i] = wf + base_[i] + E_[i]; }

    hipMemsetAsync(feat1, 0, (size_t)B * 512 * 128 * 4, stream);
    hipMemsetAsync(feat2, 0, (size_t)B * 128 * 256 * 4, stream);
    hipMemsetAsync(d_out, 0, (size_t)out_size * 4, stream);

    prep_weights<<<(PREP_TOT + NTH - 1) / NTH, NTH, 0, stream>>>(
        W[0], W[3], W[6], W[9], W[12], W[15], W[18], W[21], W[24], wf);

    // ---- SA1 ----
    fps_kernel<4096, 512, 512><<<B, 512, 0, stream>>>(pc, nxyz1);
    ball_query_kernel<<<(B * 512 + 3) / 4, NTH, 0, stream>>>(
        pc, nxyz1, idx1, B * 512, N, 512, (float)(0.2 * 0.2));
    // SA1 compute + FPS2 (hidden in the same dispatch)
    sa1_fps2<0, 64, 64, 128, 64, 512, 128><<<B * 512 + B, NTH, 0, stream>>>(
        pc, nullptr, nxyz1, idx1,
        wh[0], wl[0], wh[1], wl[1], wh[2], wl[2],
        W[1], W[2], W[4], W[5], W[7], W[8],
        feat1, 512, N,
        nxyz1, nxyz2, B * 512);

    // ---- SA2 ----
    ball_query_kernel<<<(B * 128 + 3) / 4, NTH, 0, stream>>>(
        nxyz1, nxyz2, idx2, B * 128, 512, 128, (float)(0.4 * 0.4));
    sa_mfma<128, 128, 128, 256, 32><<<B * 128 * 2, NTH, 0, stream>>>(
        nxyz1, feat1, nxyz2, idx2,
        wh[3], wl[3], wh[4], wl[4], wh[5], wl[5],
        W[10], W[11], W[13], W[14], W[16], W[17],
        feat2, 128, 512);

    // ---- SA3 / global head ----
    head_mfma<256, 256, 512, 1024><<<B * 8, NTH, 0, stream>>>(
        nxyz2, feat2,
        wh[6], wl[6], wh[7], wl[7], wh[8], wl[8],
        W[19], W[20], W[22], W[23], W[25], W[26],
        out, 128);
}

// Round 4
// 878.450 us; speedup vs baseline: 2.8549x; 1.2960x over previous
//
#include <hip/hip_runtime.h>
#include <math.h>

#define NTH 256

using short8 = __attribute__((ext_vector_type(8))) short;
using f32x4  = __attribute__((ext_vector_type(4))) float;

__device__ __forceinline__ unsigned short f2bf(float x) {
    unsigned u = __float_as_uint(x);
    u += 0x7fff + ((u >> 16) & 1);          // round-to-nearest-even
    return (unsigned short)(u >> 16);
}
__device__ __forceinline__ float bf2f(unsigned short h) {
    return __uint_as_float(((unsigned)h) << 16);
}

// ---- u64-key max helpers: DPP levels (VALU-rate) + xor16 swizzle ----
template<int CTRL>
__device__ __forceinline__ unsigned long long dpp_max(unsigned long long k) {
    unsigned lo = (unsigned)k, hi = (unsigned)(k >> 32);
    unsigned plo = (unsigned)__builtin_amdgcn_update_dpp(0, (int)lo, CTRL, 0xF, 0xF, true);
    unsigned phi = (unsigned)__builtin_amdgcn_update_dpp(0, (int)hi, CTRL, 0xF, 0xF, true);
    unsigned long long p = ((unsigned long long)phi << 32) | plo;
    return p > k ? p : k;
}
__device__ __forceinline__ unsigned long long swz16_max(unsigned long long k) {
    unsigned lo = (unsigned)k, hi = (unsigned)(k >> 32);
    unsigned plo = (unsigned)__builtin_amdgcn_ds_swizzle((int)lo, 0x401F);  // xor16
    unsigned phi = (unsigned)__builtin_amdgcn_ds_swizzle((int)hi, 0x401F);
    unsigned long long p = ((unsigned long long)phi << 32) | plo;
    return p > k ? p : k;
}

// ============================= FPS =============================
// Packed u64 key (dist-bits<<32 | ~idx): max == (max dist, lowest idx) — matches
// numpy argmax first-occurrence. One barrier/iter; in-wave reduce via DPP butterfly
// (xor1,xor2 quad_perm; half-mirror; mirror; xor16 swizzle); lanes 0/32 publish.
// Distance arithmetic op-identical to reference ((dx*dx+dy*dy)+dz*dz, RN, no fma).
template<int N, int NPOINT, int NTHR>
__device__ __forceinline__ void fps_body(
    const float* __restrict__ xyz, float* __restrict__ out_xyz, int b,
    float* __restrict__ pts, unsigned long long* __restrict__ wkey /* 2*2*NW */)
{
    constexpr int PT = N / NTHR;
    constexpr int NW = NTHR / 64;
    constexpr int NK = 2 * NW;
    const int tid  = threadIdx.x;
    const int lane = tid & 63;
    const int w    = tid >> 6;
    const float* src = xyz + (size_t)b * N * 3;
    for (int e = tid; e < N * 3; e += NTHR) pts[e] = src[e];
    __syncthreads();

    float px[PT], py[PT], pz[PT], dist[PT];
    unsigned ic[PT];
#pragma unroll
    for (int j = 0; j < PT; ++j) {
        int i = j * NTHR + tid;
        px[j] = pts[i * 3 + 0]; py[j] = pts[i * 3 + 1]; pz[j] = pts[i * 3 + 2];
        dist[j] = 1e10f;
        ic[j] = ~(unsigned)i;
    }
    if (tid == 0) {
        out_xyz[(size_t)b * NPOINT * 3 + 0] = pts[0];
        out_xyz[(size_t)b * NPOINT * 3 + 1] = pts[1];
        out_xyz[(size_t)b * NPOINT * 3 + 2] = pts[2];
    }
    int last = 0;
    for (int it = 1; it < NPOINT; ++it) {
        const float lx = pts[last * 3 + 0];
        const float ly = pts[last * 3 + 1];
        const float lz = pts[last * 3 + 2];
        unsigned long long best = 0ull;
#pragma unroll
        for (int j = 0; j < PT; ++j) {
            float dx = px[j] - lx, dy = py[j] - ly, dz = pz[j] - lz;
            float d = __fadd_rn(__fadd_rn(__fmul_rn(dx, dx), __fmul_rn(dy, dy)),
                                __fmul_rn(dz, dz));
            float nd = fminf(dist[j], d);
            dist[j] = nd;
            unsigned long long key =
                ((unsigned long long)__float_as_uint(nd) << 32) | (unsigned long long)ic[j];
            best = (key > best) ? key : best;
        }
        best = dpp_max<0xB1>(best);    // quad_perm [1,0,3,2]  : xor1
        best = dpp_max<0x4E>(best);    // quad_perm [2,3,0,1]  : xor2
        best = dpp_max<0x141>(best);   // row_half_mirror      : crosses 4-boundary
        best = dpp_max<0x140>(best);   // row_mirror           : crosses 8-boundary
        best = swz16_max(best);        // xor16 within 32-lane groups
        if ((lane & 31) == 0) wkey[(it & 1) * NK + w * 2 + (lane >> 5)] = best;
        __syncthreads();
        unsigned long long k[NK];
#pragma unroll
        for (int v = 0; v < NK; ++v) k[v] = wkey[(it & 1) * NK + v];
#pragma unroll
        for (int st = NK / 2; st > 0; st >>= 1)
#pragma unroll
            for (int v = 0; v < st; ++v) k[v] = (k[v + st] > k[v]) ? k[v + st] : k[v];
        best = k[0];
        last = (int)(~(unsigned)best);
        if (tid == 0) {
            out_xyz[((size_t)b * NPOINT + it) * 3 + 0] = pts[last * 3 + 0];
            out_xyz[((size_t)b * NPOINT + it) * 3 + 1] = pts[last * 3 + 1];
            out_xyz[((size_t)b * NPOINT + it) * 3 + 2] = pts[last * 3 + 2];
        }
    }
}

// ===================== Weight prep (device body, grid-strided) =====================
#define PREP_TOT 813056
__device__ __forceinline__ void prep_body(
    int gid, int stride,
    const float* __restrict__ w0, const float* __restrict__ w1, const float* __restrict__ w2,
    const float* __restrict__ w3, const float* __restrict__ w4, const float* __restrict__ w5,
    const float* __restrict__ w6, const float* __restrict__ w7, const float* __restrict__ w8,
    unsigned short* __restrict__ outw)
{
    const int K_[9]    = {3, 64, 64, 131, 128, 128, 259, 256, 512};
    const int N_[9]    = {64, 64, 128, 128, 128, 256, 256, 512, 1024};
    const int E_[9]    = {2048, 4096, 8192, 20480, 16384, 32768, 73728, 131072, 524288};
    const int base_[9] = {0, 4096, 12288, 28672, 69632, 102400, 167936, 315392, 577536};
    const float* W_[9] = {w0, w1, w2, w3, w4, w5, w6, w7, w8};
    for (; gid < PREP_TOT; gid += stride) {
        int i = 0, t = gid;
        while (t >= E_[i]) { t -= E_[i]; ++i; }
        const int N = N_[i];
        const int k8 = t / (N * 8);
        const int rem = t - k8 * N * 8;
        const int col = rem >> 3, j = rem & 7;
        const int k = k8 * 8 + j;
        float v = (k < K_[i]) ? W_[i][(size_t)k * N + col] : 0.f;
        unsigned short hi = f2bf(v);
        unsigned short lo = f2bf(v - bf2f(hi));
        outw[base_[i] + t] = hi;
        outw[base_[i] + E_[i] + t] = lo;
    }
}

// ===== Fused: FPS1 (blocks < nfps) + weight prep (blocks >= nfps) =====
template<int N1, int NP1, int NTHR>
__global__ __launch_bounds__(NTHR) void fps1_prep(
    const float* __restrict__ pc, float* __restrict__ nxyz1,
    const float* __restrict__ w0, const float* __restrict__ w1, const float* __restrict__ w2,
    const float* __restrict__ w3, const float* __restrict__ w4, const float* __restrict__ w5,
    const float* __restrict__ w6, const float* __restrict__ w7, const float* __restrict__ w8,
    unsigned short* __restrict__ outw, int nfps)
{
    __shared__ float pts[N1 * 3];
    __shared__ unsigned long long wkey[2 * 2 * (NTHR / 64)];
    if ((int)blockIdx.x < nfps) {
        fps_body<N1, NP1, NTHR>(pc, nxyz1, blockIdx.x, pts, wkey);
    } else {
        prep_body((blockIdx.x - nfps) * NTHR + threadIdx.x,
                  (gridDim.x - nfps) * NTHR,
                  w0, w1, w2, w3, w4, w5, w6, w7, w8, outw);
    }
}

// ========================== Ball query (unchanged) ==========================
__global__ __launch_bounds__(NTH) void ball_query_kernel(
    const float* __restrict__ xyz, const float* __restrict__ centers,
    int* __restrict__ out, int BS, int N, int S, float r2)
{
    const int wid = blockIdx.x * (NTH / 64) + (threadIdx.x >> 6);
    if (wid >= BS) return;
    const int lane = threadIdx.x & 63;
    const int b = wid / S;
    const float cx = centers[(size_t)wid * 3 + 0];
    const float cy = centers[(size_t)wid * 3 + 1];
    const float cz = centers[(size_t)wid * 3 + 2];
    const float* px = xyz + (size_t)b * N * 3;
    int count = 0, first = -1;
    for (int base = 0; base < N && count < 64; base += 64) {
        int i = base + lane;
        float dx = px[i * 3 + 0] - cx, dy = px[i * 3 + 1] - cy, dz = px[i * 3 + 2] - cz;
        float d2 = __fadd_rn(__fadd_rn(__fmul_rn(dx, dx), __fmul_rn(dy, dy)),
                             __fmul_rn(dz, dz));
        bool inb = d2 < r2;
        unsigned long long m = __ballot(inb);
        if (first < 0 && m) first = base + (__ffsll(m) - 1);
        if (inb) {
            int pos = count + (int)__popcll(m & ((1ull << lane) - 1ull));
            if (pos < 64) out[(size_t)wid * 64 + pos] = i;
        }
        count += (int)__popcll(m);
    }
    int cnt = count > 64 ? 64 : count;
    if (first < 0) first = N - 1;
    if (lane >= cnt) out[(size_t)wid * 64 + lane] = first;
}

// ===================== split-bf16 MFMA MLP layer =====================
// Wave w owns col-range [NOFF + w*NSUB/4, ...); iterates all RTILES row-tiles so
// B-frags (global/L2) are loaded ONCE per K-slice and reused across row-tiles.
// acc += Ah*Bh + Ah*Bl + Al*Bh (3x mfma_f32_16x16x32_bf16) — same K-order as before,
// bitwise-identical outputs. D: col=lane&15, row=(lane>>4)*4+reg.
template<int K, int NSUB, int NOFF, int NFULL, int RTILES, int SX, int SY, bool FINAL>
__device__ __forceinline__ void mfma_layer(
    const unsigned short* __restrict__ whi, const unsigned short* __restrict__ wlo,
    const float* __restrict__ gm, const float* __restrict__ bt,
    const unsigned short* __restrict__ Xhi, const unsigned short* __restrict__ Xlo,
    unsigned short* __restrict__ Yhi, unsigned short* __restrict__ Ylo,
    float* outp, int tid)
{
    constexpr int KP  = (K + 31) & ~31;
    constexpr int KC  = KP / 32;
    constexpr int NTW = NSUB / 64;          // 16-col tiles per wave (4 waves)
    static_assert(NSUB % 64 == 0, "col split");
    const int w = tid >> 6, lane = tid & 63;
    const int lr = lane & 15, lg = lane >> 4;
    const int colbase = NOFF + w * (NSUB / 4);

    f32x4 acc[RTILES][NTW];
#pragma unroll
    for (int m = 0; m < RTILES; ++m)
#pragma unroll
        for (int t = 0; t < NTW; ++t) acc[m][t] = f32x4{0.f, 0.f, 0.f, 0.f};

    const unsigned short* xh0 = Xhi + lr * SX + lg * 8;
    const unsigned short* xl0 = Xlo + lr * SX + lg * 8;

    for (int kc = 0; kc < KC; ++kc) {
        const size_t krow = (size_t)(kc * 4 + lg) * NFULL * 8;
        short8 bh[NTW], bl[NTW];
#pragma unroll
        for (int t = 0; t < NTW; ++t) {
            const int col = colbase + t * 16 + lr;
            bh[t] = *reinterpret_cast<const short8*>(whi + krow + (size_t)col * 8);
            bl[t] = *reinterpret_cast<const short8*>(wlo + krow + (size_t)col * 8);
        }
#pragma unroll
        for (int m = 0; m < RTILES; ++m) {
            short8 ah = *reinterpret_cast<const short8*>(xh0 + m * 16 * SX + kc * 32);
            short8 al = *reinterpret_cast<const short8*>(xl0 + m * 16 * SX + kc * 32);
#pragma unroll
            for (int t = 0; t < NTW; ++t) {
                acc[m][t] = __builtin_amdgcn_mfma_f32_16x16x32_bf16(ah, bh[t], acc[m][t], 0, 0, 0);
                acc[m][t] = __builtin_amdgcn_mfma_f32_16x16x32_bf16(ah, bl[t], acc[m][t], 0, 0, 0);
                acc[m][t] = __builtin_amdgcn_mfma_f32_16x16x32_bf16(al, bh[t], acc[m][t], 0, 0, 0);
            }
        }
    }
#pragma unroll
    for (int t = 0; t < NTW; ++t) {
        const int col = colbase + t * 16 + lr;
        const float gv = gm[col], bv = bt[col];
        if constexpr (FINAL) {
            float mx = 0.f;
#pragma unroll
            for (int m = 0; m < RTILES; ++m)
#pragma unroll
                for (int r = 0; r < 4; ++r)
                    mx = fmaxf(mx, fmaxf(fmaf(acc[m][t][r], gv, bv), 0.f));
            mx = fmaxf(mx, __shfl_xor(mx, 16));
            mx = fmaxf(mx, __shfl_xor(mx, 32));
            if (lg == 0)
                atomicMax(reinterpret_cast<int*>(outp) + col, __float_as_int(mx));
        } else {
#pragma unroll
            for (int m = 0; m < RTILES; ++m)
#pragma unroll
                for (int r = 0; r < 4; ++r) {
                    float v = fmaxf(fmaf(acc[m][t][r], gv, bv), 0.f);
                    unsigned short hi = f2bf(v);
                    unsigned short lo = f2bf(v - bf2f(hi));
                    const int row = m * 16 + lg * 4 + r;
                    Yhi[row * SY + col] = hi;
                    Ylo[row * SY + col] = lo;
                }
        }
    }
}

// ===================== SA body: gather + 3x MFMA-MLP + maxpool =====================
template<int CF, int C0, int C1, int C2, int R>
struct SaCfg {
    static constexpr int CIN = 3 + CF;
    static constexpr int KP0 = (CIN + 31) & ~31;
    static constexpr int SX = KP0 + 8, SY1 = C0 + 8, SY2 = C1 + 8;
    static constexpr int RT = R / 16;
    static constexpr int HALVES = 64 / R;
    static constexpr int OFF_Y1 = 0;
    static constexpr int OFF_X = 2 * R * SY1;
    static constexpr int XSZ = 2 * R * SX, Y2SZ = 2 * R * SY2;
    static constexpr int TOT = OFF_X + (XSZ > Y2SZ ? XSZ : Y2SZ);
};

template<int CF, int C0, int C1, int C2, int R>
__device__ __forceinline__ void sa_body(
    unsigned short* __restrict__ sm, int flat,
    const float* __restrict__ src_xyz, const float* __restrict__ src_feat,
    const float* __restrict__ centers, const int* __restrict__ nbr,
    const unsigned short* __restrict__ w0h, const unsigned short* __restrict__ w0l,
    const unsigned short* __restrict__ w1h, const unsigned short* __restrict__ w1l,
    const unsigned short* __restrict__ w2h, const unsigned short* __restrict__ w2l,
    const float* __restrict__ g0, const float* __restrict__ b0,
    const float* __restrict__ g1, const float* __restrict__ b1,
    const float* __restrict__ g2, const float* __restrict__ b2,
    float* __restrict__ out_feat, int S, int N)
{
    using C = SaCfg<CF, C0, C1, C2, R>;
    const int tid  = threadIdx.x;
    const int half = flat % C::HALVES;
    const int bs   = flat / C::HALVES;
    const int b    = bs / S;
    const int* __restrict__ myidx = nbr + (size_t)bs * 64 + half * R;

    unsigned short* Xhi = sm + C::OFF_X;    unsigned short* Xlo = Xhi + R * C::SX;
    unsigned short* Y1h = sm + C::OFF_Y1;   unsigned short* Y1l = Y1h + R * C::SY1;
    unsigned short* Y2h = sm + C::OFF_X;    unsigned short* Y2l = Y2h + R * C::SY2;

    const float cx = centers[(size_t)bs * 3 + 0];
    const float cy = centers[(size_t)bs * 3 + 1];
    const float cz = centers[(size_t)bs * 3 + 2];
    for (int e = tid; e < R * C::KP0; e += NTH) {
        const int r = e / C::KP0, c = e - (e / C::KP0) * C::KP0;
        const int pid = myidx[r];
        float v = 0.f;
        if (c < 3) {
            float p = src_xyz[((size_t)b * N + pid) * 3 + c];
            v = p - (c == 0 ? cx : (c == 1 ? cy : cz));
        } else if constexpr (CF > 0) {
            if (c < C::CIN) v = src_feat[((size_t)b * N + pid) * CF + (c - 3)];
        }
        unsigned short hi = f2bf(v);
        unsigned short lo = f2bf(v - bf2f(hi));
        Xhi[r * C::SX + c] = hi; Xlo[r * C::SX + c] = lo;
    }
    __syncthreads();
    mfma_layer<C::CIN, C0, 0, C0, C::RT, C::SX, C::SY1, false>(
        w0h, w0l, g0, b0, Xhi, Xlo, Y1h, Y1l, nullptr, tid);
    __syncthreads();
    mfma_layer<C0, C1, 0, C1, C::RT, C::SY1, C::SY2, false>(
        w1h, w1l, g1, b1, Y1h, Y1l, Y2h, Y2l, nullptr, tid);
    __syncthreads();
    mfma_layer<C1, C2, 0, C2, C::RT, C::SY2, 0, true>(
        w2h, w2l, g2, b2, Y2h, Y2l, nullptr, nullptr,
        out_feat + (size_t)bs * C2, tid);
}

template<int CF, int C0, int C1, int C2, int R>
__global__ __launch_bounds__(NTH) void sa_mfma(
    const float* __restrict__ src_xyz, const float* __restrict__ src_feat,
    const float* __restrict__ centers, const int* __restrict__ nbr,
    const unsigned short* __restrict__ w0h, const unsigned short* __restrict__ w0l,
    const unsigned short* __restrict__ w1h, const unsigned short* __restrict__ w1l,
    const unsigned short* __restrict__ w2h, const unsigned short* __restrict__ w2l,
    const float* __restrict__ g0, const float* __restrict__ b0,
    const float* __restrict__ g1, const float* __restrict__ b1,
    const float* __restrict__ g2, const float* __restrict__ b2,
    float* __restrict__ out_feat, int S, int N)
{
    __shared__ __align__(16) unsigned short sm[SaCfg<CF, C0, C1, C2, R>::TOT];
    sa_body<CF, C0, C1, C2, R>(sm, blockIdx.x, src_xyz, src_feat, centers, nbr,
                               w0h, w0l, w1h, w1l, w2h, w2l,
                               g0, b0, g1, b1, g2, b2, out_feat, S, N);
}

// ===== Merged: SA1 (blocks < NSA) + FPS2 (blocks >= NSA), FPS2 hides under SA1 =====
template<int CF, int C0, int C1, int C2, int R, int N2, int NP2>
__global__ __launch_bounds__(NTH) void sa1_fps2(
    const float* __restrict__ src_xyz, const float* __restrict__ src_feat,
    const float* __restrict__ centers, const int* __restrict__ nbr,
    const unsigned short* __restrict__ w0h, const unsigned short* __restrict__ w0l,
    const unsigned short* __restrict__ w1h, const unsigned short* __restrict__ w1l,
    const unsigned short* __restrict__ w2h, const unsigned short* __restrict__ w2l,
    const float* __restrict__ g0, const float* __restrict__ b0,
    const float* __restrict__ g1, const float* __restrict__ b1,
    const float* __restrict__ g2, const float* __restrict__ b2,
    float* __restrict__ out_feat, int S, int N,
    const float* __restrict__ fps_in, float* __restrict__ fps_out, int NSA)
{
    constexpr size_t SAB = (size_t)SaCfg<CF, C0, C1, C2, R>::TOT * 2;
    constexpr size_t FPB = (size_t)N2 * 3 * 4 + 2 * 2 * (NTH / 64) * 8;
    constexpr size_t BYTES = SAB > FPB ? SAB : FPB;
    __shared__ __align__(16) char smraw[BYTES];
    if ((int)blockIdx.x < NSA) {
        sa_body<CF, C0, C1, C2, R>((unsigned short*)smraw, blockIdx.x,
                                   src_xyz, src_feat, centers, nbr,
                                   w0h, w0l, w1h, w1l, w2h, w2l,
                                   g0, b0, g1, b1, g2, b2, out_feat, S, N);
    } else {
        fps_body<N2, NP2, NTH>(fps_in, fps_out, blockIdx.x - NSA,
                               (float*)smraw,
                               (unsigned long long*)(smraw + (size_t)N2 * 3 * 4));
    }
}

// ===================== Head: concat + 3x MFMA-MLP + global maxpool =====================
template<int CF, int C0, int C1, int C2>
__global__ __launch_bounds__(NTH) void head_mfma(
    const float* __restrict__ xyz, const float* __restrict__ feat,
    const unsigned short* __restrict__ w0h, const unsigned short* __restrict__ w0l,
    const unsigned short* __restrict__ w1h, const unsigned short* __restrict__ w1l,
    const unsigned short* __restrict__ w2h, const unsigned short* __restrict__ w2l,
    const float* __restrict__ g0, const float* __restrict__ b0,
    const float* __restrict__ g1, const float* __restrict__ b1,
    const float* __restrict__ g2, const float* __restrict__ b2,
    float* __restrict__ out, int Np)
{
    constexpr int R = 16;
    constexpr int CIN = 3 + CF;
    constexpr int KP0 = (CIN + 31) & ~31;
    constexpr int SX = KP0 + 8, SY1 = C0 + 8, SY2 = C1 + 8;
    constexpr int OFF_Y1 = 0;
    constexpr int OFF_X  = 2 * R * SY1;
    constexpr int XSZ = 2 * R * SX, Y2SZ = 2 * R * SY2;
    constexpr int TOT = OFF_X + (XSZ > Y2SZ ? XSZ : Y2SZ);
    __shared__ __align__(16) unsigned short sm[TOT];

    const int tid = threadIdx.x;
    const int chunks = Np / R;
    const int b  = blockIdx.x / chunks;
    const int r0 = (blockIdx.x % chunks) * R;

    unsigned short* Xhi = sm + OFF_X;   unsigned short* Xlo = Xhi + R * SX;
    unsigned short* Y1h = sm + OFF_Y1;  unsigned short* Y1l = Y1h + R * SY1;
    unsigned short* Y2h = sm + OFF_X;   unsigned short* Y2l = Y2h + R * SY2;

    for (int e = tid; e < R * KP0; e += NTH) {
        const int r = e / KP0, c = e - (e / KP0) * KP0;
        const int row = r0 + r;
        float v = 0.f;
        if (c < 3)        v = xyz[((size_t)b * Np + row) * 3 + c];
        else if (c < CIN) v = feat[((size_t)b * Np + row) * CF + (c - 3)];
        unsigned short hi = f2bf(v);
        unsigned short lo = f2bf(v - bf2f(hi));
        Xhi[r * SX + c] = hi; Xlo[r * SX + c] = lo;
    }
    __syncthreads();
    mfma_layer<CIN, C0, 0, C0, 1, SX, SY1, false>(w0h, w0l, g0, b0, Xhi, Xlo, Y1h, Y1l, nullptr, tid);
    __syncthreads();
    mfma_layer<C0, C1, 0, C1, 1, SY1, SY2, false>(w1h, w1l, g1, b1, Y1h, Y1l, Y2h, Y2l, nullptr, tid);
    __syncthreads();
    float* op = out + (size_t)b * C2;
    mfma_layer<C1, C2 / 2, 0,      C2, 1, SY2, 0, true>(w2h, w2l, g2, b2, Y2h, Y2l, nullptr, nullptr, op, tid);
    mfma_layer<C1, C2 / 2, C2 / 2, C2, 1, SY2, 0, true>(w2h, w2l, g2, b2, Y2h, Y2l, nullptr, nullptr, op, tid);
}

// ============================== launch ==============================
extern "C" void kernel_launch(void* const* d_in, const int* in_sizes, int n_in,
                              void* d_out, int out_size, void* d_ws, size_t ws_size,
                              hipStream_t stream)
{
    (void)in_sizes; (void)n_in; (void)ws_size;
    const int B = 32, N = 4096;
    const float* pc = (const float*)d_in[0];
    const float* W[27];
    for (int i = 0; i < 27; ++i) W[i] = (const float*)d_in[1 + i];
    float* out = (float*)d_out;

    char* ws = (char*)d_ws;
    size_t off = 0;
    auto take = [&](size_t bytes) {
        void* p = ws + off;
        off += (bytes + 255) & ~(size_t)255;
        return p;
    };
    float* nxyz1 = (float*)take((size_t)B * 512 * 3 * 4);
    int*   idx1  = (int*)  take((size_t)B * 512 * 64 * 4);
    float* feat1 = (float*)take((size_t)B * 512 * 128 * 4);
    float* nxyz2 = (float*)take((size_t)B * 128 * 3 * 4);
    int*   idx2  = (int*)  take((size_t)B * 128 * 64 * 4);
    float* feat2 = (float*)take((size_t)B * 128 * 256 * 4);
    unsigned short* wf = (unsigned short*)take((size_t)1626112 * 2);

    const int E_[9]    = {2048, 4096, 8192, 20480, 16384, 32768, 73728, 131072, 524288};
    const int base_[9] = {0, 4096, 12288, 28672, 69632, 102400, 167936, 315392, 577536};
    const unsigned short* wh[9]; const unsigned short* wl[9];
    for (int i = 0; i < 9; ++i) { wh[i] = wf + base_[i]; wl[i] = wf + base_[i] + E_[i]; }

    hipMemsetAsync(feat1, 0, (size_t)B * 512 * 128 * 4, stream);
    hipMemsetAsync(feat2, 0, (size_t)B * 128 * 256 * 4, stream);
    hipMemsetAsync(d_out, 0, (size_t)out_size * 4, stream);

    // ---- FPS1 + weight prep (fused; 32 FPS blocks + 512 prep blocks) ----
    fps1_prep<4096, 512, 512><<<32 + 512, 512, 0, stream>>>(
        pc, nxyz1,
        W[0], W[3], W[6], W[9], W[12], W[15], W[18], W[21], W[24],
        wf, 32);

    // ---- SA1 ----
    ball_query_kernel<<<(B * 512 + 3) / 4, NTH, 0, stream>>>(
        pc, nxyz1, idx1, B * 512, N, 512, (float)(0.2 * 0.2));
    sa1_fps2<0, 64, 64, 128, 64, 512, 128><<<B * 512 + B, NTH, 0, stream>>>(
        pc, nullptr, nxyz1, idx1,
        wh[0], wl[0], wh[1], wl[1], wh[2], wl[2],
        W[1], W[2], W[4], W[5], W[7], W[8],
        feat1, 512, N,
        nxyz1, nxyz2, B * 512);

    // ---- SA2 ----
    ball_query_kernel<<<(B * 128 + 3) / 4, NTH, 0, stream>>>(
        nxyz1, nxyz2, idx2, B * 128, 512, 128, (float)(0.4 * 0.4));
    sa_mfma<128, 128, 128, 256, 32><<<B * 128 * 2, NTH, 0, stream>>>(
        nxyz1, feat1, nxyz2, idx2,
        wh[3], wl[3], wh[4], wl[4], wh[5], wl[5],
        W[10], W[11], W[13], W[14], W[16], W[17],
        feat2, 128, 512);

    // ---- SA3 / global head ----
    head_mfma<256, 256, 512, 1024><<<B * 8, NTH, 0, stream>>>(
        nxyz2, feat2,
        wh[6], wl[6], wh[7], wl[7], wh[8], wl[8],
        W[19], W[20], W[22], W[23], W[25], W[26],
        out, 128);
}

// Round 5
// 807.811 us; speedup vs baseline: 3.1045x; 1.0874x over previous
//
#include <hip/hip_runtime.h>
#include <math.h>

#define NTH 256

using short8 = __attribute__((ext_vector_type(8))) short;
using f32x4  = __attribute__((ext_vector_type(4))) float;

__device__ __forceinline__ unsigned short f2bf(float x) {
    unsigned u = __float_as_uint(x);
    u += 0x7fff + ((u >> 16) & 1);          // round-to-nearest-even
    return (unsigned short)(u >> 16);
}
__device__ __forceinline__ float bf2f(unsigned short h) {
    return __uint_as_float(((unsigned)h) << 16);
}

// ---- u64-key max with (x,y,z) payload, one DPP level ----
template<int CTRL>
__device__ __forceinline__ void dppmaxp(unsigned long long& k, float& x, float& y, float& z) {
    unsigned lo = (unsigned)k, hi = (unsigned)(k >> 32);
    unsigned plo = (unsigned)__builtin_amdgcn_update_dpp(0, (int)lo, CTRL, 0xF, 0xF, true);
    unsigned phi = (unsigned)__builtin_amdgcn_update_dpp(0, (int)hi, CTRL, 0xF, 0xF, true);
    int pxi = __builtin_amdgcn_update_dpp(0, __float_as_int(x), CTRL, 0xF, 0xF, true);
    int pyi = __builtin_amdgcn_update_dpp(0, __float_as_int(y), CTRL, 0xF, 0xF, true);
    int pzi = __builtin_amdgcn_update_dpp(0, __float_as_int(z), CTRL, 0xF, 0xF, true);
    unsigned long long p = ((unsigned long long)phi << 32) | plo;
    bool sw = p > k;            // keys unique (idx embedded); 0-filled lanes never win
    k = sw ? p : k;
    x = sw ? __int_as_float(pxi) : x;
    y = sw ? __int_as_float(pyi) : y;
    z = sw ? __int_as_float(pzi) : z;
}

// ============================= FPS =============================
// Points live in registers (no pts[] LDS). Winner coords carried as payload through
// an all-DPP 64-lane reduce (quad_perm xor1/xor2, half-mirror, mirror, ROW_BCAST15,
// ROW_BCAST31 -> lane 63), then a small cross-wave payload tree. One barrier/iter.
// Key = (dist-bits<<32)|~idx: max == (max dist, lowest idx) — numpy argmax semantics.
// Distance arithmetic op-identical to reference ((dx*dx+dy*dy)+dz*dz, RN, no fma).
template<int N, int NPOINT, int NTHR>
__device__ __forceinline__ void fps_body(
    const float* __restrict__ xyz, float* __restrict__ out_xyz, int b,
    unsigned long long* __restrict__ wk, float* __restrict__ wx,
    float* __restrict__ wy, float* __restrict__ wz)   // each sized [2 * NTHR/64]
{
    constexpr int PT = N / NTHR;
    constexpr int NW = NTHR / 64;
    const int tid  = threadIdx.x;
    const int lane = tid & 63;
    const int w    = tid >> 6;
    const float* src = xyz + (size_t)b * N * 3;

    float px[PT], py[PT], pz[PT], dist[PT];
#pragma unroll
    for (int j = 0; j < PT; ++j) {
        int i = j * NTHR + tid;
        px[j] = src[i * 3 + 0]; py[j] = src[i * 3 + 1]; pz[j] = src[i * 3 + 2];
        dist[j] = 1e10f;
    }
    float lx = src[0], ly = src[1], lz = src[2];
    if (tid == 0) {
        out_xyz[(size_t)b * NPOINT * 3 + 0] = lx;
        out_xyz[(size_t)b * NPOINT * 3 + 1] = ly;
        out_xyz[(size_t)b * NPOINT * 3 + 2] = lz;
    }
    for (int it = 1; it < NPOINT; ++it) {
        float bd = -1.f, bx = 0.f, by = 0.f, bz = 0.f;
        unsigned bic = 0;
#pragma unroll
        for (int j = 0; j < PT; ++j) {
            float dx = px[j] - lx, dy = py[j] - ly, dz = pz[j] - lz;
            float d = __fadd_rn(__fadd_rn(__fmul_rn(dx, dx), __fmul_rn(dy, dy)),
                                __fmul_rn(dz, dz));
            float nd = fminf(dist[j], d);
            dist[j] = nd;
            bool sw = nd > bd;   // strict > keeps lowest idx (j ascending)
            bd  = sw ? nd : bd;
            bic = sw ? ~(unsigned)(j * NTHR + tid) : bic;
            bx  = sw ? px[j] : bx;
            by  = sw ? py[j] : by;
            bz  = sw ? pz[j] : bz;
        }
        unsigned long long key =
            ((unsigned long long)__float_as_uint(bd) << 32) | (unsigned long long)bic;
        dppmaxp<0xB1>(key, bx, by, bz);    // quad_perm xor1
        dppmaxp<0x4E>(key, bx, by, bz);    // quad_perm xor2
        dppmaxp<0x141>(key, bx, by, bz);   // row_half_mirror (xor4)
        dppmaxp<0x140>(key, bx, by, bz);   // row_mirror (xor8)
        dppmaxp<0x142>(key, bx, by, bz);   // ROW_BCAST15: 16->32 combine
        dppmaxp<0x143>(key, bx, by, bz);   // ROW_BCAST31: 32->64, lane63 = wave max
        const int p = (it & 1) * NW;
        if (lane == 63) { wk[p + w] = key; wx[p + w] = bx; wy[p + w] = by; wz[p + w] = bz; }
        __syncthreads();
        unsigned long long K0[NW]; float X0[NW], Y0[NW], Z0[NW];
#pragma unroll
        for (int v = 0; v < NW; ++v) {
            K0[v] = wk[p + v]; X0[v] = wx[p + v]; Y0[v] = wy[p + v]; Z0[v] = wz[p + v];
        }
#pragma unroll
        for (int st = NW / 2; st > 0; st >>= 1)
#pragma unroll
            for (int v = 0; v < st; ++v) {
                bool sw = K0[v + st] > K0[v];
                K0[v] = sw ? K0[v + st] : K0[v];
                X0[v] = sw ? X0[v + st] : X0[v];
                Y0[v] = sw ? Y0[v + st] : Y0[v];
                Z0[v] = sw ? Z0[v + st] : Z0[v];
            }
        lx = X0[0]; ly = Y0[0]; lz = Z0[0];
        if (tid == 0) {
            out_xyz[((size_t)b * NPOINT + it) * 3 + 0] = lx;
            out_xyz[((size_t)b * NPOINT + it) * 3 + 1] = ly;
            out_xyz[((size_t)b * NPOINT + it) * 3 + 2] = lz;
        }
    }
}

// ===================== Weight prep (grid-strided body) =====================
// Frag layout per layer: [KP/8][N][8] bf16, hi then lo. Layers 3 and 6 (SA2/head L0)
// are channel-PERMUTED: feat first (c'=0..CF-1), xyz last (c'=CF..CF+2) — matches the
// gather's aligned feat stores.
#define PREP_TOT 813056
__device__ __forceinline__ void prep_body(
    int gid, int stride,
    const float* __restrict__ w0, const float* __restrict__ w1, const float* __restrict__ w2,
    const float* __restrict__ w3, const float* __restrict__ w4, const float* __restrict__ w5,
    const float* __restrict__ w6, const float* __restrict__ w7, const float* __restrict__ w8,
    unsigned short* __restrict__ outw)
{
    const int K_[9]    = {3, 64, 64, 131, 128, 128, 259, 256, 512};
    const int N_[9]    = {64, 64, 128, 128, 128, 256, 256, 512, 1024};
    const int E_[9]    = {2048, 4096, 8192, 20480, 16384, 32768, 73728, 131072, 524288};
    const int base_[9] = {0, 4096, 12288, 28672, 69632, 102400, 167936, 315392, 577536};
    const int PCF_[9]  = {0, 0, 0, 128, 0, 0, 256, 0, 0};
    const float* W_[9] = {w0, w1, w2, w3, w4, w5, w6, w7, w8};
    for (; gid < PREP_TOT; gid += stride) {
        int i = 0, t = gid;
        while (t >= E_[i]) { t -= E_[i]; ++i; }
        const int Nn = N_[i];
        const int k8 = t / (Nn * 8);
        const int rem = t - k8 * Nn * 8;
        const int col = rem >> 3, j = rem & 7;
        const int k = k8 * 8 + j;
        float v = 0.f;
        if (k < K_[i]) {
            int ks = k;
            const int pcf = PCF_[i];
            if (pcf > 0) ks = (k < pcf) ? (k + 3) : (k - pcf);
            v = W_[i][(size_t)ks * Nn + col];
        }
        unsigned short hi = f2bf(v);
        unsigned short lo = f2bf(v - bf2f(hi));
        outw[base_[i] + t] = hi;
        outw[base_[i] + E_[i] + t] = lo;
    }
}

// ===== Fused: FPS1 (blocks < nfps) + weight prep (blocks >= nfps) =====
template<int N1, int NP1>
__global__ __launch_bounds__(NTH) void fps1_prep(
    const float* __restrict__ pc, float* __restrict__ nxyz1,
    const float* __restrict__ w0, const float* __restrict__ w1, const float* __restrict__ w2,
    const float* __restrict__ w3, const float* __restrict__ w4, const float* __restrict__ w5,
    const float* __restrict__ w6, const float* __restrict__ w7, const float* __restrict__ w8,
    unsigned short* __restrict__ outw, int nfps)
{
    __shared__ unsigned long long fwk[2 * (NTH / 64)];
    __shared__ float fwx[2 * (NTH / 64)], fwy[2 * (NTH / 64)], fwz[2 * (NTH / 64)];
    if ((int)blockIdx.x < nfps) {
        fps_body<N1, NP1, NTH>(pc, nxyz1, blockIdx.x, fwk, fwx, fwy, fwz);
    } else {
        prep_body((blockIdx.x - nfps) * NTH + threadIdx.x,
                  (gridDim.x - nfps) * NTH,
                  w0, w1, w2, w3, w4, w5, w6, w7, w8, outw);
    }
}

// ========================== Ball query (unchanged) ==========================
__global__ __launch_bounds__(NTH) void ball_query_kernel(
    const float* __restrict__ xyz, const float* __restrict__ centers,
    int* __restrict__ out, int BS, int N, int S, float r2)
{
    const int wid = blockIdx.x * (NTH / 64) + (threadIdx.x >> 6);
    if (wid >= BS) return;
    const int lane = threadIdx.x & 63;
    const int b = wid / S;
    const float cx = centers[(size_t)wid * 3 + 0];
    const float cy = centers[(size_t)wid * 3 + 1];
    const float cz = centers[(size_t)wid * 3 + 2];
    const float* px = xyz + (size_t)b * N * 3;
    int count = 0, first = -1;
    for (int base = 0; base < N && count < 64; base += 64) {
        int i = base + lane;
        float dx = px[i * 3 + 0] - cx, dy = px[i * 3 + 1] - cy, dz = px[i * 3 + 2] - cz;
        float d2 = __fadd_rn(__fadd_rn(__fmul_rn(dx, dx), __fmul_rn(dy, dy)),
                             __fmul_rn(dz, dz));
        bool inb = d2 < r2;
        unsigned long long m = __ballot(inb);
        if (first < 0 && m) first = base + (__ffsll(m) - 1);
        if (inb) {
            int pos = count + (int)__popcll(m & ((1ull << lane) - 1ull));
            if (pos < 64) out[(size_t)wid * 64 + pos] = i;
        }
        count += (int)__popcll(m);
    }
    int cnt = count > 64 ? 64 : count;
    if (first < 0) first = N - 1;
    if (lane >= cnt) out[(size_t)wid * 64 + lane] = first;
}

// ===================== split-bf16 MFMA MLP layer (unchanged from R4) =====================
template<int K, int NSUB, int NOFF, int NFULL, int RTILES, int SX, int SY, bool FINAL>
__device__ __forceinline__ void mfma_layer(
    const unsigned short* __restrict__ whi, const unsigned short* __restrict__ wlo,
    const float* __restrict__ gm, const float* __restrict__ bt,
    const unsigned short* __restrict__ Xhi, const unsigned short* __restrict__ Xlo,
    unsigned short* __restrict__ Yhi, unsigned short* __restrict__ Ylo,
    float* outp, int tid)
{
    constexpr int KP  = (K + 31) & ~31;
    constexpr int KC  = KP / 32;
    constexpr int NTW = NSUB / 64;
    static_assert(NSUB % 64 == 0, "col split");
    const int w = tid >> 6, lane = tid & 63;
    const int lr = lane & 15, lg = lane >> 4;
    const int colbase = NOFF + w * (NSUB / 4);

    f32x4 acc[RTILES][NTW];
#pragma unroll
    for (int m = 0; m < RTILES; ++m)
#pragma unroll
        for (int t = 0; t < NTW; ++t) acc[m][t] = f32x4{0.f, 0.f, 0.f, 0.f};

    const unsigned short* xh0 = Xhi + lr * SX + lg * 8;
    const unsigned short* xl0 = Xlo + lr * SX + lg * 8;

    for (int kc = 0; kc < KC; ++kc) {
        const size_t krow = (size_t)(kc * 4 + lg) * NFULL * 8;
        short8 bh[NTW], bl[NTW];
#pragma unroll
        for (int t = 0; t < NTW; ++t) {
            const int col = colbase + t * 16 + lr;
            bh[t] = *reinterpret_cast<const short8*>(whi + krow + (size_t)col * 8);
            bl[t] = *reinterpret_cast<const short8*>(wlo + krow + (size_t)col * 8);
        }
#pragma unroll
        for (int m = 0; m < RTILES; ++m) {
            short8 ah = *reinterpret_cast<const short8*>(xh0 + m * 16 * SX + kc * 32);
            short8 al = *reinterpret_cast<const short8*>(xl0 + m * 16 * SX + kc * 32);
#pragma unroll
            for (int t = 0; t < NTW; ++t) {
                acc[m][t] = __builtin_amdgcn_mfma_f32_16x16x32_bf16(ah, bh[t], acc[m][t], 0, 0, 0);
                acc[m][t] = __builtin_amdgcn_mfma_f32_16x16x32_bf16(ah, bl[t], acc[m][t], 0, 0, 0);
                acc[m][t] = __builtin_amdgcn_mfma_f32_16x16x32_bf16(al, bh[t], acc[m][t], 0, 0, 0);
            }
        }
    }
#pragma unroll
    for (int t = 0; t < NTW; ++t) {
        const int col = colbase + t * 16 + lr;
        const float gv = gm[col], bv = bt[col];
        if constexpr (FINAL) {
            float mx = 0.f;
#pragma unroll
            for (int m = 0; m < RTILES; ++m)
#pragma unroll
                for (int r = 0; r < 4; ++r)
                    mx = fmaxf(mx, fmaxf(fmaf(acc[m][t][r], gv, bv), 0.f));
            mx = fmaxf(mx, __shfl_xor(mx, 16));
            mx = fmaxf(mx, __shfl_xor(mx, 32));
            if (lg == 0)
                atomicMax(reinterpret_cast<int*>(outp) + col, __float_as_int(mx));
        } else {
#pragma unroll
            for (int m = 0; m < RTILES; ++m)
#pragma unroll
                for (int r = 0; r < 4; ++r) {
                    float v = fmaxf(fmaf(acc[m][t][r], gv, bv), 0.f);
                    unsigned short hi = f2bf(v);
                    unsigned short lo = f2bf(v - bf2f(hi));
                    const int row = m * 16 + lg * 4 + r;
                    Yhi[row * SY + col] = hi;
                    Ylo[row * SY + col] = lo;
                }
        }
    }
}

// ===================== SA body: fast gather + 3x MFMA-MLP + maxpool =====================
// Channel layout (CF>0): feat at c'=0..CF-1 (float4 loads, ushort4 LDS stores),
// xyz at c'=CF..CF+2, zero-pad to KP0. Weights permuted identically in prep.
template<int CF, int C0, int C1, int C2, int R>
struct SaCfg {
    static constexpr int CIN = 3 + CF;
    static constexpr int KP0 = (CIN + 31) & ~31;
    static constexpr int SX = KP0 + 8, SY1 = C0 + 8, SY2 = C1 + 8;
    static constexpr int RT = R / 16;
    static constexpr int HALVES = 64 / R;
    static constexpr int OFF_Y1 = 0;
    static constexpr int OFF_X = 2 * R * SY1;
    static constexpr int XSZ = 2 * R * SX, Y2SZ = 2 * R * SY2;
    static constexpr int TOT = OFF_X + (XSZ > Y2SZ ? XSZ : Y2SZ);
};

template<int CF, int C0, int C1, int C2, int R>
__device__ __forceinline__ void sa_body(
    unsigned short* __restrict__ sm, int flat,
    const float* __restrict__ src_xyz, const float* __restrict__ src_feat,
    const float* __restrict__ centers, const int* __restrict__ nbr,
    const unsigned short* __restrict__ w0h, const unsigned short* __restrict__ w0l,
    const unsigned short* __restrict__ w1h, const unsigned short* __restrict__ w1l,
    const unsigned short* __restrict__ w2h, const unsigned short* __restrict__ w2l,
    const float* __restrict__ g0, const float* __restrict__ b0,
    const float* __restrict__ g1, const float* __restrict__ b1,
    const float* __restrict__ g2, const float* __restrict__ b2,
    float* __restrict__ out_feat, int S, int N)
{
    using C = SaCfg<CF, C0, C1, C2, R>;
    constexpr int TPR = NTH / R;                 // threads per row
    const int tid  = threadIdx.x;
    const int half = flat % C::HALVES;
    const int bs   = flat / C::HALVES;
    const int b    = bs / S;
    const int* __restrict__ myidx = nbr + (size_t)bs * 64 + half * R;

    unsigned short* Xhi = sm + C::OFF_X;    unsigned short* Xlo = Xhi + R * C::SX;
    unsigned short* Y1h = sm + C::OFF_Y1;   unsigned short* Y1l = Y1h + R * C::SY1;
    unsigned short* Y2h = sm + C::OFF_X;    unsigned short* Y2l = Y2h + R * C::SY2;

    const float cx = centers[(size_t)bs * 3 + 0];
    const float cy = centers[(size_t)bs * 3 + 1];
    const float cz = centers[(size_t)bs * 3 + 2];

    {
        const int r = tid / TPR, s = tid % TPR;  // TPR is pow2 -> shifts
        const int pid = myidx[r];
        unsigned short* xh = Xhi + r * C::SX;
        unsigned short* xl = Xlo + r * C::SX;
        if constexpr (CF > 0) {
            constexpr int CPT = CF / TPR;        // feat channels per thread (mult of 4)
            const float* frow = src_feat + ((size_t)b * N + pid) * CF + s * CPT;
#pragma unroll
            for (int q = 0; q < CPT / 4; ++q) {
                float4 v4 = *reinterpret_cast<const float4*>(frow + q * 4);
                ushort4 h, l;
                h.x = f2bf(v4.x); l.x = f2bf(v4.x - bf2f(h.x));
                h.y = f2bf(v4.y); l.y = f2bf(v4.y - bf2f(h.y));
                h.z = f2bf(v4.z); l.z = f2bf(v4.z - bf2f(h.z));
                h.w = f2bf(v4.w); l.w = f2bf(v4.w - bf2f(h.w));
                *reinterpret_cast<ushort4*>(xh + s * CPT + q * 4) = h;
                *reinterpret_cast<ushort4*>(xl + s * CPT + q * 4) = l;
            }
        }
        if (s < 3) {
            float p = src_xyz[((size_t)b * N + pid) * 3 + s]
                      - (s == 0 ? cx : (s == 1 ? cy : cz));
            unsigned short hi = f2bf(p), lo = f2bf(p - bf2f(hi));
            xh[CF + s] = hi; xl[CF + s] = lo;
        }
        constexpr int PADPER = (C::KP0 - C::CIN + TPR - 1) / TPR;
#pragma unroll
        for (int q = 0; q < PADPER; ++q) {
            int c = C::CIN + s * PADPER + q;
            if (c < C::KP0) { xh[c] = 0; xl[c] = 0; }
        }
    }
    __syncthreads();
    mfma_layer<C::CIN, C0, 0, C0, C::RT, C::SX, C::SY1, false>(
        w0h, w0l, g0, b0, Xhi, Xlo, Y1h, Y1l, nullptr, tid);
    __syncthreads();
    mfma_layer<C0, C1, 0, C1, C::RT, C::SY1, C::SY2, false>(
        w1h, w1l, g1, b1, Y1h, Y1l, Y2h, Y2l, nullptr, tid);
    __syncthreads();
    mfma_layer<C1, C2, 0, C2, C::RT, C::SY2, 0, true>(
        w2h, w2l, g2, b2, Y2h, Y2l, nullptr, nullptr,
        out_feat + (size_t)bs * C2, tid);
}

template<int CF, int C0, int C1, int C2, int R>
__global__ __launch_bounds__(NTH) void sa_mfma(
    const float* __restrict__ src_xyz, const float* __restrict__ src_feat,
    const float* __restrict__ centers, const int* __restrict__ nbr,
    const unsigned short* __restrict__ w0h, const unsigned short* __restrict__ w0l,
    const unsigned short* __restrict__ w1h, const unsigned short* __restrict__ w1l,
    const unsigned short* __restrict__ w2h, const unsigned short* __restrict__ w2l,
    const float* __restrict__ g0, const float* __restrict__ b0,
    const float* __restrict__ g1, const float* __restrict__ b1,
    const float* __restrict__ g2, const float* __restrict__ b2,
    float* __restrict__ out_feat, int S, int N)
{
    __shared__ __align__(16) unsigned short sm[SaCfg<CF, C0, C1, C2, R>::TOT];
    sa_body<CF, C0, C1, C2, R>(sm, blockIdx.x, src_xyz, src_feat, centers, nbr,
                               w0h, w0l, w1h, w1l, w2h, w2l,
                               g0, b0, g1, b1, g2, b2, out_feat, S, N);
}

// ===== Merged: SA1 (blocks < NSA) + FPS2 (blocks >= NSA), FPS2 hides under SA1 =====
template<int CF, int C0, int C1, int C2, int R, int N2, int NP2>
__global__ __launch_bounds__(NTH) void sa1_fps2(
    const float* __restrict__ src_xyz, const float* __restrict__ src_feat,
    const float* __restrict__ centers, const int* __restrict__ nbr,
    const unsigned short* __restrict__ w0h, const unsigned short* __restrict__ w0l,
    const unsigned short* __restrict__ w1h, const unsigned short* __restrict__ w1l,
    const unsigned short* __restrict__ w2h, const unsigned short* __restrict__ w2l,
    const float* __restrict__ g0, const float* __restrict__ b0,
    const float* __restrict__ g1, const float* __restrict__ b1,
    const float* __restrict__ g2, const float* __restrict__ b2,
    float* __restrict__ out_feat, int S, int N,
    const float* __restrict__ fps_in, float* __restrict__ fps_out, int NSA)
{
    __shared__ __align__(16) unsigned short sm[SaCfg<CF, C0, C1, C2, R>::TOT];
    __shared__ unsigned long long fwk[2 * (NTH / 64)];
    __shared__ float fwx[2 * (NTH / 64)], fwy[2 * (NTH / 64)], fwz[2 * (NTH / 64)];
    if ((int)blockIdx.x < NSA) {
        sa_body<CF, C0, C1, C2, R>(sm, blockIdx.x,
                                   src_xyz, src_feat, centers, nbr,
                                   w0h, w0l, w1h, w1l, w2h, w2l,
                                   g0, b0, g1, b1, g2, b2, out_feat, S, N);
    } else {
        fps_body<N2, NP2, NTH>(fps_in, fps_out, blockIdx.x - NSA, fwk, fwx, fwy, fwz);
    }
}

// ===================== Head: concat + 3x MFMA-MLP + global maxpool =====================
template<int CF, int C0, int C1, int C2>
__global__ __launch_bounds__(NTH) void head_mfma(
    const float* __restrict__ xyz, const float* __restrict__ feat,
    const unsigned short* __restrict__ w0h, const unsigned short* __restrict__ w0l,
    const unsigned short* __restrict__ w1h, const unsigned short* __restrict__ w1l,
    const unsigned short* __restrict__ w2h, const unsigned short* __restrict__ w2l,
    const float* __restrict__ g0, const float* __restrict__ b0,
    const float* __restrict__ g1, const float* __restrict__ b1,
    const float* __restrict__ g2, const float* __restrict__ b2,
    float* __restrict__ out, int Np)
{
    constexpr int R = 16;
    constexpr int CIN = 3 + CF;                  // 259, permuted: feat 0..255, xyz 256..258
    constexpr int KP0 = (CIN + 31) & ~31;        // 288
    constexpr int SX = KP0 + 8, SY1 = C0 + 8, SY2 = C1 + 8;
    constexpr int OFF_Y1 = 0;
    constexpr int OFF_X  = 2 * R * SY1;
    constexpr int XSZ = 2 * R * SX, Y2SZ = 2 * R * SY2;
    constexpr int TOT = OFF_X + (XSZ > Y2SZ ? XSZ : Y2SZ);
    __shared__ __align__(16) unsigned short sm[TOT];
    constexpr int TPR = NTH / R;                 // 16

    const int tid = threadIdx.x;
    const int chunks = Np / R;
    const int b  = blockIdx.x / chunks;
    const int r0 = (blockIdx.x % chunks) * R;

    unsigned short* Xhi = sm + OFF_X;   unsigned short* Xlo = Xhi + R * SX;
    unsigned short* Y1h = sm + OFF_Y1;  unsigned short* Y1l = Y1h + R * SY1;
    unsigned short* Y2h = sm + OFF_X;   unsigned short* Y2l = Y2h + R * SY2;

    {
        const int r = tid / TPR, s = tid % TPR;
        const int row = r0 + r;
        unsigned short* xh = Xhi + r * SX;
        unsigned short* xl = Xlo + r * SX;
        constexpr int CPT = CF / TPR;            // 16
        const float* frow = feat + ((size_t)b * Np + row) * CF + s * CPT;
#pragma unroll
        for (int q = 0; q < CPT / 4; ++q) {
            float4 v4 = *reinterpret_cast<const float4*>(frow + q * 4);
            ushort4 h, l;
            h.x = f2bf(v4.x); l.x = f2bf(v4.x - bf2f(h.x));
            h.y = f2bf(v4.y); l.y = f2bf(v4.y - bf2f(h.y));
            h.z = f2bf(v4.z); l.z = f2bf(v4.z - bf2f(h.z));
            h.w = f2bf(v4.w); l.w = f2bf(v4.w - bf2f(h.w));
            *reinterpret_cast<ushort4*>(xh + s * CPT + q * 4) = h;
            *reinterpret_cast<ushort4*>(xl + s * CPT + q * 4) = l;
        }
        if (s < 3) {
            float p = xyz[((size_t)b * Np + row) * 3 + s];
            unsigned short hi = f2bf(p), lo = f2bf(p - bf2f(hi));
            xh[CF + s] = hi; xl[CF + s] = lo;
        }
        constexpr int PADPER = (KP0 - CIN + TPR - 1) / TPR;  // 2
#pragma unroll
        for (int q = 0; q < PADPER; ++q) {
            int c = CIN + s * PADPER + q;
            if (c < KP0) { xh[c] = 0; xl[c] = 0; }
        }
    }
    __syncthreads();
    mfma_layer<CIN, C0, 0, C0, 1, SX, SY1, false>(w0h, w0l, g0, b0, Xhi, Xlo, Y1h, Y1l, nullptr, tid);
    __syncthreads();
    mfma_layer<C0, C1, 0, C1, 1, SY1, SY2, false>(w1h, w1l, g1, b1, Y1h, Y1l, Y2h, Y2l, nullptr, tid);
    __syncthreads();
    float* op = out + (size_t)b * C2;
    mfma_layer<C1, C2 / 2, 0,      C2, 1, SY2, 0, true>(w2h, w2l, g2, b2, Y2h, Y2l, nullptr, nullptr, op, tid);
    mfma_layer<C1, C2 / 2, C2 / 2, C2, 1, SY2, 0, true>(w2h, w2l, g2, b2, Y2h, Y2l, nullptr, nullptr, op, tid);
}

// ============================== launch ==============================
extern "C" void kernel_launch(void* const* d_in, const int* in_sizes, int n_in,
                              void* d_out, int out_size, void* d_ws, size_t ws_size,
                              hipStream_t stream)
{
    (void)in_sizes; (void)n_in; (void)ws_size;
    const int B = 32, N = 4096;
    const float* pc = (const float*)d_in[0];
    const float* W[27];
    for (int i = 0; i < 27; ++i) W[i] = (const float*)d_in[1 + i];
    float* out = (float*)d_out;

    char* ws = (char*)d_ws;
    size_t off = 0;
    auto take = [&](size_t bytes) {
        void* p = ws + off;
        off += (bytes + 255) & ~(size_t)255;
        return p;
    };
    float* nxyz1 = (float*)take((size_t)B * 512 * 3 * 4);
    int*   idx1  = (int*)  take((size_t)B * 512 * 64 * 4);
    float* feat1 = (float*)take((size_t)B * 512 * 128 * 4);
    float* nxyz2 = (float*)take((size_t)B * 128 * 3 * 4);
    int*   idx2  = (int*)  take((size_t)B * 128 * 64 * 4);
    float* feat2 = (float*)take((size_t)B * 128 * 256 * 4);
    unsigned short* wf = (unsigned short*)take((size_t)1626112 * 2);

    const int E_[9]    = {2048, 4096, 8192, 20480, 16384, 32768, 73728, 131072, 524288};
    const int base_[9] = {0, 4096, 12288, 28672, 69632, 102400, 167936, 315392, 577536};
    const unsigned short* wh[9]; const unsigned short* wl[9];
    for (int i = 0; i < 9; ++i) { wh[i] = wf + base_[i]; wl[i] = wf + base_[i] + E_[i]; }

    hipMemsetAsync(feat1, 0, (size_t)B * 512 * 128 * 4, stream);
    hipMemsetAsync(feat2, 0, (size_t)B * 128 * 256 * 4, stream);
    hipMemsetAsync(d_out, 0, (size_t)out_size * 4, stream);

    // ---- FPS1 + weight prep (fused; 32 FPS blocks + 512 prep blocks) ----
    fps1_prep<4096, 512><<<32 + 512, NTH, 0, stream>>>(
        pc, nxyz1,
        W[0], W[3], W[6], W[9], W[12], W[15], W[18], W[21], W[24],
        wf, 32);

    // ---- SA1 (+hidden FPS2) ----
    ball_query_kernel<<<(B * 512 + 3) / 4, NTH, 0, stream>>>(
        pc, nxyz1, idx1, B * 512, N, 512, (float)(0.2 * 0.2));
    sa1_fps2<0, 64, 64, 128, 64, 512, 128><<<B * 512 + B, NTH, 0, stream>>>(
        pc, nullptr, nxyz1, idx1,
        wh[0], wl[0], wh[1], wl[1], wh[2], wl[2],
        W[1], W[2], W[4], W[5], W[7], W[8],
        feat1, 512, N,
        nxyz1, nxyz2, B * 512);

    // ---- SA2 ----
    ball_query_kernel<<<(B * 128 + 3) / 4, NTH, 0, stream>>>(
        nxyz1, nxyz2, idx2, B * 128, 512, 128, (float)(0.4 * 0.4));
    sa_mfma<128, 128, 128, 256, 32><<<B * 128 * 2, NTH, 0, stream>>>(
        nxyz1, feat1, nxyz2, idx2,
        wh[3], wl[3], wh[4], wl[4], wh[5], wl[5],
        W[10], W[11], W[13], W[14], W[16], W[17],
        feat2, 128, 512);

    // ---- SA3 / global head ----
    head_mfma<256, 256, 512, 1024><<<B * 8, NTH, 0, stream>>>(
        nxyz2, feat2,
        wh[6], wl[6], wh[7], wl[7], wh[8], wl[8],
        W[19], W[20], W[22], W[23], W[25], W[26],
        out, 128);
}

// Round 6
// 721.188 us; speedup vs baseline: 3.4774x; 1.1201x over previous
//
#include <hip/hip_runtime.h>
#include <math.h>

#define NTH 256

using short8 = __attribute__((ext_vector_type(8))) short;
using f32x4  = __attribute__((ext_vector_type(4))) float;

__device__ __forceinline__ unsigned short f2bf(float x) {
    unsigned u = __float_as_uint(x);
    u += 0x7fff + ((u >> 16) & 1);          // round-to-nearest-even
    return (unsigned short)(u >> 16);
}
__device__ __forceinline__ float bf2f(unsigned short h) {
    return __uint_as_float(((unsigned)h) << 16);
}

// ---- u64-key max, one DPP level (key-only: 2 dpp + cmp64 + 2 cndmask) ----
template<int CTRL>
__device__ __forceinline__ unsigned long long dppmax(unsigned long long k) {
    unsigned lo = (unsigned)k, hi = (unsigned)(k >> 32);
    unsigned plo = (unsigned)__builtin_amdgcn_update_dpp(0, (int)lo, CTRL, 0xF, 0xF, true);
    unsigned phi = (unsigned)__builtin_amdgcn_update_dpp(0, (int)hi, CTRL, 0xF, 0xF, true);
    unsigned long long p = ((unsigned long long)phi << 32) | plo;
    return p > k ? p : k;   // 0-filled lanes never win (keys strictly > 0)
}

// ============================= FPS =============================
// Key = (dist-bits<<32)|~idx: u64 max == (max dist, lowest idx) — numpy argmax
// first-occurrence semantics. Distance arithmetic op-identical to reference
// ((dx*dx+dy*dy)+dz*dz, RN, no fma). NO GLOBAL OPS inside the loop: winner coords
// are buffered in LDS (ctr) and flushed once at the end — avoids the per-barrier
// s_waitcnt vmcnt(0) drain of an in-loop global store (~300-900 cy/iter).
template<int N, int NPOINT, int NTHR>
__device__ __forceinline__ void fps_body(
    const float* __restrict__ xyz, float* __restrict__ out_xyz, int b,
    float* __restrict__ pts /*N*3*/, float* __restrict__ ctr /*NPOINT*3*/,
    unsigned long long* __restrict__ wkey /*2*NW*/)
{
    constexpr int PT = N / NTHR;
    constexpr int NW = NTHR / 64;
    const int tid  = threadIdx.x;
    const int lane = tid & 63;
    const int w    = tid >> 6;
    const float* src = xyz + (size_t)b * N * 3;

    for (int e = tid; e < N * 3; e += NTHR) pts[e] = src[e];

    float px[PT], py[PT], pz[PT], dist[PT];
    unsigned klo[PT];
#pragma unroll
    for (int j = 0; j < PT; ++j) {
        int i = j * NTHR + tid;
        px[j] = src[i * 3 + 0]; py[j] = src[i * 3 + 1]; pz[j] = src[i * 3 + 2];
        dist[j] = 1e10f;
        klo[j] = ~(unsigned)i;
    }
    if (tid == 0) { ctr[0] = src[0]; ctr[1] = src[1]; ctr[2] = src[2]; }
    __syncthreads();

    int last = 0;
    for (int it = 1; it < NPOINT; ++it) {
        const float lx = pts[last * 3 + 0];
        const float ly = pts[last * 3 + 1];
        const float lz = pts[last * 3 + 2];
        unsigned long long best = 0ull;
#pragma unroll
        for (int j = 0; j < PT; ++j) {
            float dx = px[j] - lx, dy = py[j] - ly, dz = pz[j] - lz;
            float d = __fadd_rn(__fadd_rn(__fmul_rn(dx, dx), __fmul_rn(dy, dy)),
                                __fmul_rn(dz, dz));
            float nd = fminf(dist[j], d);
            dist[j] = nd;
            unsigned long long key =
                ((unsigned long long)__float_as_uint(nd) << 32) | (unsigned long long)klo[j];
            best = (key > best) ? key : best;
        }
        best = dppmax<0xB1>(best);    // quad_perm xor1
        best = dppmax<0x4E>(best);    // quad_perm xor2
        best = dppmax<0x141>(best);   // row_half_mirror (crosses 4)
        best = dppmax<0x140>(best);   // row_mirror (crosses 8)
        best = dppmax<0x142>(best);   // ROW_BCAST15 (16->32)
        best = dppmax<0x143>(best);   // ROW_BCAST31 (32->64): lane63 = wave max
        const int p = (it & 1) * NW;
        if (lane == 63) wkey[p + w] = best;
        __syncthreads();
        unsigned long long K0[NW];
#pragma unroll
        for (int v = 0; v < NW; ++v) K0[v] = wkey[p + v];
#pragma unroll
        for (int st = NW / 2; st > 0; st >>= 1)
#pragma unroll
            for (int v = 0; v < st; ++v) K0[v] = (K0[v + st] > K0[v]) ? K0[v + st] : K0[v];
        last = (int)(~(unsigned)K0[0]);
        if (tid == 0) {
            ctr[it * 3 + 0] = pts[last * 3 + 0];
            ctr[it * 3 + 1] = pts[last * 3 + 1];
            ctr[it * 3 + 2] = pts[last * 3 + 2];
        }
    }
    __syncthreads();
    float* dst = out_xyz + (size_t)b * NPOINT * 3;
    for (int e = tid; e < NPOINT * 3; e += NTHR) dst[e] = ctr[e];
}

// ===================== Weight prep (grid-strided body) =====================
// Frag layout per layer: [KP/8][N][8] bf16, hi then lo. Layers 3 and 6 (SA2/head L0)
// are channel-PERMUTED: feat first, xyz last — matches the gather's aligned stores.
#define PREP_TOT 813056
__device__ __forceinline__ void prep_body(
    int gid, int stride,
    const float* __restrict__ w0, const float* __restrict__ w1, const float* __restrict__ w2,
    const float* __restrict__ w3, const float* __restrict__ w4, const float* __restrict__ w5,
    const float* __restrict__ w6, const float* __restrict__ w7, const float* __restrict__ w8,
    unsigned short* __restrict__ outw)
{
    const int K_[9]    = {3, 64, 64, 131, 128, 128, 259, 256, 512};
    const int N_[9]    = {64, 64, 128, 128, 128, 256, 256, 512, 1024};
    const int E_[9]    = {2048, 4096, 8192, 20480, 16384, 32768, 73728, 131072, 524288};
    const int base_[9] = {0, 4096, 12288, 28672, 69632, 102400, 167936, 315392, 577536};
    const int PCF_[9]  = {0, 0, 0, 128, 0, 0, 256, 0, 0};
    const float* W_[9] = {w0, w1, w2, w3, w4, w5, w6, w7, w8};
    for (; gid < PREP_TOT; gid += stride) {
        int i = 0, t = gid;
        while (t >= E_[i]) { t -= E_[i]; ++i; }
        const int Nn = N_[i];
        const int k8 = t / (Nn * 8);
        const int rem = t - k8 * Nn * 8;
        const int col = rem >> 3, j = rem & 7;
        const int k = k8 * 8 + j;
        float v = 0.f;
        if (k < K_[i]) {
            int ks = k;
            const int pcf = PCF_[i];
            if (pcf > 0) ks = (k < pcf) ? (k + 3) : (k - pcf);
            v = W_[i][(size_t)ks * Nn + col];
        }
        unsigned short hi = f2bf(v);
        unsigned short lo = f2bf(v - bf2f(hi));
        outw[base_[i] + t] = hi;
        outw[base_[i] + E_[i] + t] = lo;
    }
}

// ===== Fused: FPS1 (blocks < nfps) + weight prep (blocks >= nfps) =====
template<int N1, int NP1>
__global__ __launch_bounds__(NTH) void fps1_prep(
    const float* __restrict__ pc, float* __restrict__ nxyz1,
    const float* __restrict__ w0, const float* __restrict__ w1, const float* __restrict__ w2,
    const float* __restrict__ w3, const float* __restrict__ w4, const float* __restrict__ w5,
    const float* __restrict__ w6, const float* __restrict__ w7, const float* __restrict__ w8,
    unsigned short* __restrict__ outw, int nfps)
{
    __shared__ float pts[N1 * 3];
    __shared__ float ctr[NP1 * 3];
    __shared__ unsigned long long fwk[2 * (NTH / 64)];
    if ((int)blockIdx.x < nfps) {
        fps_body<N1, NP1, NTH>(pc, nxyz1, blockIdx.x, pts, ctr, fwk);
    } else {
        prep_body((blockIdx.x - nfps) * NTH + threadIdx.x,
                  (gridDim.x - nfps) * NTH,
                  w0, w1, w2, w3, w4, w5, w6, w7, w8, outw);
    }
}

// ========================== Ball query (unchanged) ==========================
__global__ __launch_bounds__(NTH) void ball_query_kernel(
    const float* __restrict__ xyz, const float* __restrict__ centers,
    int* __restrict__ out, int BS, int N, int S, float r2)
{
    const int wid = blockIdx.x * (NTH / 64) + (threadIdx.x >> 6);
    if (wid >= BS) return;
    const int lane = threadIdx.x & 63;
    const int b = wid / S;
    const float cx = centers[(size_t)wid * 3 + 0];
    const float cy = centers[(size_t)wid * 3 + 1];
    const float cz = centers[(size_t)wid * 3 + 2];
    const float* px = xyz + (size_t)b * N * 3;
    int count = 0, first = -1;
    for (int base = 0; base < N && count < 64; base += 64) {
        int i = base + lane;
        float dx = px[i * 3 + 0] - cx, dy = px[i * 3 + 1] - cy, dz = px[i * 3 + 2] - cz;
        float d2 = __fadd_rn(__fadd_rn(__fmul_rn(dx, dx), __fmul_rn(dy, dy)),
                             __fmul_rn(dz, dz));
        bool inb = d2 < r2;
        unsigned long long m = __ballot(inb);
        if (first < 0 && m) first = base + (__ffsll(m) - 1);
        if (inb) {
            int pos = count + (int)__popcll(m & ((1ull << lane) - 1ull));
            if (pos < 64) out[(size_t)wid * 64 + pos] = i;
        }
        count += (int)__popcll(m);
    }
    int cnt = count > 64 ? 64 : count;
    if (first < 0) first = N - 1;
    if (lane >= cnt) out[(size_t)wid * 64 + lane] = first;
}

// ===================== split-bf16 MFMA MLP layer (unchanged) =====================
template<int K, int NSUB, int NOFF, int NFULL, int RTILES, int SX, int SY, bool FINAL>
__device__ __forceinline__ void mfma_layer(
    const unsigned short* __restrict__ whi, const unsigned short* __restrict__ wlo,
    const float* __restrict__ gm, const float* __restrict__ bt,
    const unsigned short* __restrict__ Xhi, const unsigned short* __restrict__ Xlo,
    unsigned short* __restrict__ Yhi, unsigned short* __restrict__ Ylo,
    float* outp, int tid)
{
    constexpr int KP  = (K + 31) & ~31;
    constexpr int KC  = KP / 32;
    constexpr int NTW = NSUB / 64;
    static_assert(NSUB % 64 == 0, "col split");
    const int w = tid >> 6, lane = tid & 63;
    const int lr = lane & 15, lg = lane >> 4;
    const int colbase = NOFF + w * (NSUB / 4);

    f32x4 acc[RTILES][NTW];
#pragma unroll
    for (int m = 0; m < RTILES; ++m)
#pragma unroll
        for (int t = 0; t < NTW; ++t) acc[m][t] = f32x4{0.f, 0.f, 0.f, 0.f};

    const unsigned short* xh0 = Xhi + lr * SX + lg * 8;
    const unsigned short* xl0 = Xlo + lr * SX + lg * 8;

    for (int kc = 0; kc < KC; ++kc) {
        const size_t krow = (size_t)(kc * 4 + lg) * NFULL * 8;
        short8 bh[NTW], bl[NTW];
#pragma unroll
        for (int t = 0; t < NTW; ++t) {
            const int col = colbase + t * 16 + lr;
            bh[t] = *reinterpret_cast<const short8*>(whi + krow + (size_t)col * 8);
            bl[t] = *reinterpret_cast<const short8*>(wlo + krow + (size_t)col * 8);
        }
#pragma unroll
        for (int m = 0; m < RTILES; ++m) {
            short8 ah = *reinterpret_cast<const short8*>(xh0 + m * 16 * SX + kc * 32);
            short8 al = *reinterpret_cast<const short8*>(xl0 + m * 16 * SX + kc * 32);
#pragma unroll
            for (int t = 0; t < NTW; ++t) {
                acc[m][t] = __builtin_amdgcn_mfma_f32_16x16x32_bf16(ah, bh[t], acc[m][t], 0, 0, 0);
                acc[m][t] = __builtin_amdgcn_mfma_f32_16x16x32_bf16(ah, bl[t], acc[m][t], 0, 0, 0);
                acc[m][t] = __builtin_amdgcn_mfma_f32_16x16x32_bf16(al, bh[t], acc[m][t], 0, 0, 0);
            }
        }
    }
#pragma unroll
    for (int t = 0; t < NTW; ++t) {
        const int col = colbase + t * 16 + lr;
        const float gv = gm[col], bv = bt[col];
        if constexpr (FINAL) {
            float mx = 0.f;
#pragma unroll
            for (int m = 0; m < RTILES; ++m)
#pragma unroll
                for (int r = 0; r < 4; ++r)
                    mx = fmaxf(mx, fmaxf(fmaf(acc[m][t][r], gv, bv), 0.f));
            mx = fmaxf(mx, __shfl_xor(mx, 16));
            mx = fmaxf(mx, __shfl_xor(mx, 32));
            if (lg == 0)
                atomicMax(reinterpret_cast<int*>(outp) + col, __float_as_int(mx));
        } else {
#pragma unroll
            for (int m = 0; m < RTILES; ++m)
#pragma unroll
                for (int r = 0; r < 4; ++r) {
                    float v = fmaxf(fmaf(acc[m][t][r], gv, bv), 0.f);
                    unsigned short hi = f2bf(v);
                    unsigned short lo = f2bf(v - bf2f(hi));
                    const int row = m * 16 + lg * 4 + r;
                    Yhi[row * SY + col] = hi;
                    Ylo[row * SY + col] = lo;
                }
        }
    }
}

// ===================== SA body: fast gather + 3x MFMA-MLP + maxpool =====================
template<int CF, int C0, int C1, int C2, int R>
struct SaCfg {
    static constexpr int CIN = 3 + CF;
    static constexpr int KP0 = (CIN + 31) & ~31;
    static constexpr int SX = KP0 + 8, SY1 = C0 + 8, SY2 = C1 + 8;
    static constexpr int RT = R / 16;
    static constexpr int HALVES = 64 / R;
    static constexpr int OFF_Y1 = 0;
    static constexpr int OFF_X = 2 * R * SY1;
    static constexpr int XSZ = 2 * R * SX, Y2SZ = 2 * R * SY2;
    static constexpr int TOT = OFF_X + (XSZ > Y2SZ ? XSZ : Y2SZ);
};

template<int CF, int C0, int C1, int C2, int R>
__device__ __forceinline__ void sa_body(
    unsigned short* __restrict__ sm, int flat,
    const float* __restrict__ src_xyz, const float* __restrict__ src_feat,
    const float* __restrict__ centers, const int* __restrict__ nbr,
    const unsigned short* __restrict__ w0h, const unsigned short* __restrict__ w0l,
    const unsigned short* __restrict__ w1h, const unsigned short* __restrict__ w1l,
    const unsigned short* __restrict__ w2h, const unsigned short* __restrict__ w2l,
    const float* __restrict__ g0, const float* __restrict__ b0,
    const float* __restrict__ g1, const float* __restrict__ b1,
    const float* __restrict__ g2, const float* __restrict__ b2,
    float* __restrict__ out_feat, int S, int N)
{
    using C = SaCfg<CF, C0, C1, C2, R>;
    constexpr int TPR = NTH / R;
    const int tid  = threadIdx.x;
    const int half = flat % C::HALVES;
    const int bs   = flat / C::HALVES;
    const int b    = bs / S;
    const int* __restrict__ myidx = nbr + (size_t)bs * 64 + half * R;

    unsigned short* Xhi = sm + C::OFF_X;    unsigned short* Xlo = Xhi + R * C::SX;
    unsigned short* Y1h = sm + C::OFF_Y1;   unsigned short* Y1l = Y1h + R * C::SY1;
    unsigned short* Y2h = sm + C::OFF_X;    unsigned short* Y2l = Y2h + R * C::SY2;

    const float cx = centers[(size_t)bs * 3 + 0];
    const float cy = centers[(size_t)bs * 3 + 1];
    const float cz = centers[(size_t)bs * 3 + 2];

    {
        const int r = tid / TPR, s = tid % TPR;
        const int pid = myidx[r];
        unsigned short* xh = Xhi + r * C::SX;
        unsigned short* xl = Xlo + r * C::SX;
        if constexpr (CF > 0) {
            constexpr int CPT = CF / TPR;
            const float* frow = src_feat + ((size_t)b * N + pid) * CF + s * CPT;
#pragma unroll
            for (int q = 0; q < CPT / 4; ++q) {
                float4 v4 = *reinterpret_cast<const float4*>(frow + q * 4);
                ushort4 h, l;
                h.x = f2bf(v4.x); l.x = f2bf(v4.x - bf2f(h.x));
                h.y = f2bf(v4.y); l.y = f2bf(v4.y - bf2f(h.y));
                h.z = f2bf(v4.z); l.z = f2bf(v4.z - bf2f(h.z));
                h.w = f2bf(v4.w); l.w = f2bf(v4.w - bf2f(h.w));
                *reinterpret_cast<ushort4*>(xh + s * CPT + q * 4) = h;
                *reinterpret_cast<ushort4*>(xl + s * CPT + q * 4) = l;
            }
        }
        if (s < 3) {
            float p = src_xyz[((size_t)b * N + pid) * 3 + s]
                      - (s == 0 ? cx : (s == 1 ? cy : cz));
            unsigned short hi = f2bf(p), lo = f2bf(p - bf2f(hi));
            xh[CF + s] = hi; xl[CF + s] = lo;
        }
        constexpr int PADPER = (C::KP0 - C::CIN + TPR - 1) / TPR;
#pragma unroll
        for (int q = 0; q < PADPER; ++q) {
            int c = C::CIN + s * PADPER + q;
            if (c < C::KP0) { xh[c] = 0; xl[c] = 0; }
        }
    }
    __syncthreads();
    mfma_layer<C::CIN, C0, 0, C0, C::RT, C::SX, C::SY1, false>(
        w0h, w0l, g0, b0, Xhi, Xlo, Y1h, Y1l, nullptr, tid);
    __syncthreads();
    mfma_layer<C0, C1, 0, C1, C::RT, C::SY1, C::SY2, false>(
        w1h, w1l, g1, b1, Y1h, Y1l, Y2h, Y2l, nullptr, tid);
    __syncthreads();
    mfma_layer<C1, C2, 0, C2, C::RT, C::SY2, 0, true>(
        w2h, w2l, g2, b2, Y2h, Y2l, nullptr, nullptr,
        out_feat + (size_t)bs * C2, tid);
}

template<int CF, int C0, int C1, int C2, int R>
__global__ __launch_bounds__(NTH) void sa_mfma(
    const float* __restrict__ src_xyz, const float* __restrict__ src_feat,
    const float* __restrict__ centers, const int* __restrict__ nbr,
    const unsigned short* __restrict__ w0h, const unsigned short* __restrict__ w0l,
    const unsigned short* __restrict__ w1h, const unsigned short* __restrict__ w1l,
    const unsigned short* __restrict__ w2h, const unsigned short* __restrict__ w2l,
    const float* __restrict__ g0, const float* __restrict__ b0,
    const float* __restrict__ g1, const float* __restrict__ b1,
    const float* __restrict__ g2, const float* __restrict__ b2,
    float* __restrict__ out_feat, int S, int N)
{
    __shared__ __align__(16) unsigned short sm[SaCfg<CF, C0, C1, C2, R>::TOT];
    sa_body<CF, C0, C1, C2, R>(sm, blockIdx.x, src_xyz, src_feat, centers, nbr,
                               w0h, w0l, w1h, w1l, w2h, w2l,
                               g0, b0, g1, b1, g2, b2, out_feat, S, N);
}

// ===== Merged: SA1 (blocks < NSA) + FPS2 (blocks >= NSA), FPS2 hides under SA1 =====
template<int CF, int C0, int C1, int C2, int R, int N2, int NP2>
__global__ __launch_bounds__(NTH) void sa1_fps2(
    const float* __restrict__ src_xyz, const float* __restrict__ src_feat,
    const float* __restrict__ centers, const int* __restrict__ nbr,
    const unsigned short* __restrict__ w0h, const unsigned short* __restrict__ w0l,
    const unsigned short* __restrict__ w1h, const unsigned short* __restrict__ w1l,
    const unsigned short* __restrict__ w2h, const unsigned short* __restrict__ w2l,
    const float* __restrict__ g0, const float* __restrict__ b0,
    const float* __restrict__ g1, const float* __restrict__ b1,
    const float* __restrict__ g2, const float* __restrict__ b2,
    float* __restrict__ out_feat, int S, int N,
    const float* __restrict__ fps_in, float* __restrict__ fps_out, int NSA)
{
    __shared__ __align__(16) unsigned short sm[SaCfg<CF, C0, C1, C2, R>::TOT];
    __shared__ float fpts[N2 * 3];
    __shared__ float fctr[NP2 * 3];
    __shared__ unsigned long long fwk[2 * (NTH / 64)];
    if ((int)blockIdx.x < NSA) {
        sa_body<CF, C0, C1, C2, R>(sm, blockIdx.x,
                                   src_xyz, src_feat, centers, nbr,
                                   w0h, w0l, w1h, w1l, w2h, w2l,
                                   g0, b0, g1, b1, g2, b2, out_feat, S, N);
    } else {
        fps_body<N2, NP2, NTH>(fps_in, fps_out, blockIdx.x - NSA, fpts, fctr, fwk);
    }
}

// ===================== Head: concat + 3x MFMA-MLP + global maxpool =====================
template<int CF, int C0, int C1, int C2>
__global__ __launch_bounds__(NTH) void head_mfma(
    const float* __restrict__ xyz, const float* __restrict__ feat,
    const unsigned short* __restrict__ w0h, const unsigned short* __restrict__ w0l,
    const unsigned short* __restrict__ w1h, const unsigned short* __restrict__ w1l,
    const unsigned short* __restrict__ w2h, const unsigned short* __restrict__ w2l,
    const float* __restrict__ g0, const float* __restrict__ b0,
    const float* __restrict__ g1, const float* __restrict__ b1,
    const float* __restrict__ g2, const float* __restrict__ b2,
    float* __restrict__ out, int Np)
{
    constexpr int R = 16;
    constexpr int CIN = 3 + CF;
    constexpr int KP0 = (CIN + 31) & ~31;
    constexpr int SX = KP0 + 8, SY1 = C0 + 8, SY2 = C1 + 8;
    constexpr int OFF_Y1 = 0;
    constexpr int OFF_X  = 2 * R * SY1;
    constexpr int XSZ = 2 * R * SX, Y2SZ = 2 * R * SY2;
    constexpr int TOT = OFF_X + (XSZ > Y2SZ ? XSZ : Y2SZ);
    __shared__ __align__(16) unsigned short sm[TOT];
    constexpr int TPR = NTH / R;

    const int tid = threadIdx.x;
    const int chunks = Np / R;
    const int b  = blockIdx.x / chunks;
    const int r0 = (blockIdx.x % chunks) * R;

    unsigned short* Xhi = sm + OFF_X;   unsigned short* Xlo = Xhi + R * SX;
    unsigned short* Y1h = sm + OFF_Y1;  unsigned short* Y1l = Y1h + R * SY1;
    unsigned short* Y2h = sm + OFF_X;   unsigned short* Y2l = Y2h + R * SY2;

    {
        const int r = tid / TPR, s = tid % TPR;
        const int row = r0 + r;
        unsigned short* xh = Xhi + r * SX;
        unsigned short* xl = Xlo + r * SX;
        constexpr int CPT = CF / TPR;
        const float* frow = feat + ((size_t)b * Np + row) * CF + s * CPT;
#pragma unroll
        for (int q = 0; q < CPT / 4; ++q) {
            float4 v4 = *reinterpret_cast<const float4*>(frow + q * 4);
            ushort4 h, l;
            h.x = f2bf(v4.x); l.x = f2bf(v4.x - bf2f(h.x));
            h.y = f2bf(v4.y); l.y = f2bf(v4.y - bf2f(h.y));
            h.z = f2bf(v4.z); l.z = f2bf(v4.z - bf2f(h.z));
            h.w = f2bf(v4.w); l.w = f2bf(v4.w - bf2f(h.w));
            *reinterpret_cast<ushort4*>(xh + s * CPT + q * 4) = h;
            *reinterpret_cast<ushort4*>(xl + s * CPT + q * 4) = l;
        }
        if (s < 3) {
            float p = xyz[((size_t)b * Np + row) * 3 + s];
            unsigned short hi = f2bf(p), lo = f2bf(p - bf2f(hi));
            xh[CF + s] = hi; xl[CF + s] = lo;
        }
        constexpr int PADPER = (KP0 - CIN + TPR - 1) / TPR;
#pragma unroll
        for (int q = 0; q < PADPER; ++q) {
            int c = CIN + s * PADPER + q;
            if (c < KP0) { xh[c] = 0; xl[c] = 0; }
        }
    }
    __syncthreads();
    mfma_layer<CIN, C0, 0, C0, 1, SX, SY1, false>(w0h, w0l, g0, b0, Xhi, Xlo, Y1h, Y1l, nullptr, tid);
    __syncthreads();
    mfma_layer<C0, C1, 0, C1, 1, SY1, SY2, false>(w1h, w1l, g1, b1, Y1h, Y1l, Y2h, Y2l, nullptr, tid);
    __syncthreads();
    float* op = out + (size_t)b * C2;
    mfma_layer<C1, C2 / 2, 0,      C2, 1, SY2, 0, true>(w2h, w2l, g2, b2, Y2h, Y2l, nullptr, nullptr, op, tid);
    mfma_layer<C1, C2 / 2, C2 / 2, C2, 1, SY2, 0, true>(w2h, w2l, g2, b2, Y2h, Y2l, nullptr, nullptr, op, tid);
}

// ============================== launch ==============================
extern "C" void kernel_launch(void* const* d_in, const int* in_sizes, int n_in,
                              void* d_out, int out_size, void* d_ws, size_t ws_size,
                              hipStream_t stream)
{
    (void)in_sizes; (void)n_in; (void)ws_size;
    const int B = 32, N = 4096;
    const float* pc = (const float*)d_in[0];
    const float* W[27];
    for (int i = 0; i < 27; ++i) W[i] = (const float*)d_in[1 + i];
    float* out = (float*)d_out;

    char* ws = (char*)d_ws;
    size_t off = 0;
    auto take = [&](size_t bytes) {
        void* p = ws + off;
        off += (bytes + 255) & ~(size_t)255;
        return p;
    };
    float* nxyz1 = (float*)take((size_t)B * 512 * 3 * 4);
    int*   idx1  = (int*)  take((size_t)B * 512 * 64 * 4);
    float* feat1 = (float*)take((size_t)B * 512 * 128 * 4);
    float* nxyz2 = (float*)take((size_t)B * 128 * 3 * 4);
    int*   idx2  = (int*)  take((size_t)B * 128 * 64 * 4);
    float* feat2 = (float*)take((size_t)B * 128 * 256 * 4);
    unsigned short* wf = (unsigned short*)take((size_t)1626112 * 2);

    const int E_[9]    = {2048, 4096, 8192, 20480, 16384, 32768, 73728, 131072, 524288};
    const int base_[9] = {0, 4096, 12288, 28672, 69632, 102400, 167936, 315392, 577536};
    const unsigned short* wh[9]; const unsigned short* wl[9];
    for (int i = 0; i < 9; ++i) { wh[i] = wf + base_[i]; wl[i] = wf + base_[i] + E_[i]; }

    hipMemsetAsync(feat1, 0, (size_t)B * 512 * 128 * 4, stream);
    hipMemsetAsync(feat2, 0, (size_t)B * 128 * 256 * 4, stream);
    hipMemsetAsync(d_out, 0, (size_t)out_size * 4, stream);

    // ---- FPS1 + weight prep (fused; 32 FPS blocks + 512 prep blocks) ----
    fps1_prep<4096, 512><<<32 + 512, NTH, 0, stream>>>(
        pc, nxyz1,
        W[0], W[3], W[6], W[9], W[12], W[15], W[18], W[21], W[24],
        wf, 32);

    // ---- SA1 (+hidden FPS2) ----
    ball_query_kernel<<<(B * 512 + 3) / 4, NTH, 0, stream>>>(
        pc, nxyz1, idx1, B * 512, N, 512, (float)(0.2 * 0.2));
    sa1_fps2<0, 64, 64, 128, 64, 512, 128><<<B * 512 + B, NTH, 0, stream>>>(
        pc, nullptr, nxyz1, idx1,
        wh[0], wl[0], wh[1], wl[1], wh[2], wl[2],
        W[1], W[2], W[4], W[5], W[7], W[8],
        feat1, 512, N,
        nxyz1, nxyz2, B * 512);

    // ---- SA2 ----
    ball_query_kernel<<<(B * 128 + 3) / 4, NTH, 0, stream>>>(
        nxyz1, nxyz2, idx2, B * 128, 512, 128, (float)(0.4 * 0.4));
    sa_mfma<128, 128, 128, 256, 32><<<B * 128 * 2, NTH, 0, stream>>>(
        nxyz1, feat1, nxyz2, idx2,
        wh[3], wl[3], wh[4], wl[4], wh[5], wl[5],
        W[10], W[11], W[13], W[14], W[16], W[17],
        feat2, 128, 512);

    // ---- SA3 / global head ----
    head_mfma<256, 256, 512, 1024><<<B * 8, NTH, 0, stream>>>(
        nxyz2, feat2,
        wh[6], wl[6], wh[7], wl[7], wh[8], wl[8],
        W[19], W[20], W[22], W[23], W[25], W[26],
        out, 128);
}